// Round 11
// baseline (126.731 us; speedup 1.0000x reference)
//
#include <hip/hip_runtime.h>
#include <hip/hip_bf16.h>

typedef float f2 __attribute__((ext_vector_type(2)));

// ---------------- helpers ----------------

// swizzle for 4096-amp f2 LDS tile: XOR low 4 bits with bits 4-7 (bijective)
#define SWZA(i) ((i) ^ (((i) >> 4) & 15))

// complex 2x2 gate on an amplitude pair; u = {u00r,u00i,u01r,u01i,u10r,u10i,u11r,u11i}
__device__ __forceinline__ void gate1q(f2& a0, f2& a1, const float* u) {
    f2 s0 = { -a0.y, a0.x };
    f2 s1 = { -a1.y, a1.x };
    f2 n0 = u[0]*a0 + u[1]*s0 + u[2]*a1 + u[3]*s1;
    f2 n1 = u[4]*a0 + u[5]*s0 + u[6]*a1 + u[7]*s1;
    a0 = n0; a1 = n1;
}

// RX on the (a0,a1) pair: n0 = c*a0 - i*s*a1 ; n1 = -i*s*a0 + c*a1
__device__ __forceinline__ void crx_pair(f2& a0, f2& a1, float c, float s) {
    f2 t0 = { a0.y, -a0.x };
    f2 t1 = { a1.y, -a1.x };
    f2 n0 = c*a0 + s*t1;
    f2 n1 = c*a1 + s*t0;
    a0 = n0; a1 = n1;
}

// plain 1q gate over W-amp window, target bit K
template<int K, int W>
__device__ __forceinline__ void apply1q_win(f2* a, const float* u) {
    #pragma unroll
    for (int m = 0; m < W / 2; ++m) {
        const int j0 = ((m >> K) << (K + 1)) | (m & ((1 << K) - 1));
        gate1q(a[j0], a[j0 | (1 << K)], u);
    }
}

// merged (U_q then CRX(q-1,q)) : control-selected 2x2. u16 = {U | RX*U}
template<int K, int KC, int W>
__device__ __forceinline__ void apply1q_mg(f2* a, const float* u16) {
    #pragma unroll
    for (int m = 0; m < W / 2; ++m) {
        const int j0 = ((m >> K) << (K + 1)) | (m & ((1 << K) - 1));
        const float* uu = u16 + (((j0 >> KC) & 1) << 3);
        gate1q(a[j0], a[j0 | (1 << K)], uu);
    }
}

__device__ __forceinline__ void loadU16(const float* __restrict__ src, float* u) {
    #pragma unroll
    for (int k = 0; k < 16; ++k) u[k] = src[k];
}

// ---------------- kernel 1: adaptive pool ----------------
__global__ __launch_bounds__(256) void pool_kernel(const float* __restrict__ x,
                                                   float* __restrict__ p) {
    int blk = blockIdx.x;            // b*32 + j
    int b = blk >> 5, j = blk & 31;
    int c = j >> 4, dd = (j >> 2) & 3, hh = j & 3;
    const float4* xb = (const float4*)(x + (((size_t)(b * 2 + c) * 16 + dd * 4) << 12)
                                         + (size_t)hh * 1024);
    int tid = threadIdx.x;
    float sum = 0.f;
    #pragma unroll
    for (int k = 0; k < 4; ++k) {
        int f = k * 256 + tid;
        int r = f >> 4, col = f & 15;
        int off = (r >> 4) * 1024 + (r & 15) * 16 + col;
        float4 v = xb[off];
        sum += v.x + v.y + v.z + v.w;
    }
    #pragma unroll
    for (int o = 1; o < 64; o <<= 1) sum += __shfl_xor(sum, o);
    __shared__ float red[4];
    if ((tid & 63) == 0) red[tid >> 6] = sum;
    __syncthreads();
    if (tid == 0) p[blk] = (red[0] + red[1] + red[2] + red[3]) * (1.0f / 4096.0f);
}

// ---------------- kernel 2: prep + sparse passA + right chains + left gates ---------
// grid = 512: b = blk>>2, vv = (blk>>1)&1, fj = blk&1. 256 threads, ~34 KB LDS.
// Each block produces ONE left factor A_k (k = vv*2+fj), 2048 amps, 8 amps/thread.
__global__ __launch_bounds__(256) void qfused(const float* __restrict__ p,
                                              const float* __restrict__ cw,
                                              const float* __restrict__ cb,
                                              const float* __restrict__ rot1,
                                              const float* __restrict__ crx1,
                                              const float* __restrict__ rot2,
                                              const float* __restrict__ crx2,
                                              float* __restrict__ rvg,
                                              f2* __restrict__ Aout,
                                              int* __restrict__ qcnt) {
    __shared__ f2 lds[4096];
    __shared__ float pp[32];
    __shared__ float uL0[12][16];   // layer-0 merged U0..U11
    __shared__ float uB0[4][16];    // layer-0 merged U12..U15
    __shared__ float uL1[11][16];   // layer-1 merged U0..U10
    __shared__ float uR1[5][16];    // layer-1 merged U11..U15
    __shared__ float cs15l0[2];     // layer-0 CRX(15,0) c,s
    int bid = blockIdx.x;
    int b = bid >> 2, vv = (bid >> 1) & 1, fj = bid & 1;
    int tid = threadIdx.x;

    if (tid < 32) pp[tid] = p[b * 32 + tid];
    __syncthreads();
    // prep: 32 threads, one per (q, l)
    if (tid < 32) {
        int q = tid & 15, l = tid >> 4;
        float f = cb[q];
        #pragma unroll
        for (int jj = 0; jj < 32; ++jj) f += pp[jj] * cw[q * 32 + jj];
        float cr = cosf(0.5f * f), sr = sinf(0.5f * f);
        const float* rw = (l == 0 ? rot1 : rot2) + q * 3;
        float phi = rw[0], th = rw[1], om = rw[2];
        float ct = cosf(0.5f * th), st = sinf(0.5f * th);
        float aa = 0.5f * (phi + om), dd = 0.5f * (phi - om);
        float ca = cosf(aa), sa = sinf(aa), cd = cosf(dd), sd = sinf(dd);
        float R00r =  ct * ca, R00i = -ct * sa;
        float R01r = -st * cd, R01i = -st * sd;
        float R10r =  st * cd, R10i = -st * sd;
        float R11r =  ct * ca, R11i =  ct * sa;
        float u0 = cr * R00r + sr * R01i;
        float u1 = cr * R00i - sr * R01r;
        float u2 = cr * R01r + sr * R00i;
        float u3 = cr * R01i - sr * R00r;
        float u4 = cr * R10r + sr * R11i;
        float u5 = cr * R10i - sr * R11r;
        float u6 = cr * R11r + sr * R10i;
        float u7 = cr * R11i - sr * R10r;
        float g[16];
        g[0] = u0; g[1] = u1; g[2] = u2; g[3] = u3;
        g[4] = u4; g[5] = u5; g[6] = u6; g[7] = u7;
        if (q >= 1) {
            float thc = (l == 0 ? crx1 : crx2)[q - 1];
            float c2 = cosf(0.5f * thc), s2 = sinf(0.5f * thc);
            g[8]  = c2*u0 + s2*u5;  g[9]  = c2*u1 - s2*u4;
            g[10] = c2*u2 + s2*u7;  g[11] = c2*u3 - s2*u6;
            g[12] = c2*u4 + s2*u1;  g[13] = c2*u5 - s2*u0;
            g[14] = c2*u6 + s2*u3;  g[15] = c2*u7 - s2*u2;
        } else {
            #pragma unroll
            for (int k = 0; k < 8; ++k) g[8 + k] = g[k];
        }
        float* s = (l == 0) ? ((q < 12) ? uL0[q] : uB0[q - 12])
                            : ((q < 11) ? uL1[q] : uR1[q - 11]);
        #pragma unroll
        for (int k = 0; k < 16; ++k) s[k] = g[k];
        if (l == 0 && q == 15) {
            cs15l0[0] = cosf(0.5f * crx1[15]);
            cs15l0[1] = sinf(0.5f * crx1[15]);
        }
    }
    if ((bid & 3) == 0 && tid == 255) qcnt[b] = 0;   // reset head counter each call
    __syncthreads();

    // ---- right chains: one block per batch, 8 wave-3 threads, one per (j,c,bsel) ---
    if ((bid & 3) == 0 && tid >= 192 && tid < 200) {
        int idx = tid - 192;
        int j = idx & 1, c = (idx >> 1) & 1, bsel = (idx >> 2) & 1;
        f2 w[32];
        #pragma unroll
        for (int m = 0; m < 32; ++m) w[m] = f2{0.f, 0.f};
        w[j] = f2{1.f, 0.f};
        apply1q_mg<1, 0, 32>(w, uB0[0]);   // L0: U12 + CRX(11,12)
        apply1q_mg<2, 1, 32>(w, uB0[1]);
        apply1q_mg<3, 2, 32>(w, uB0[2]);
        apply1q_mg<4, 3, 32>(w, uB0[3]);
        #pragma unroll
        for (int m = 0; m < 32; ++m)
            if (((m >> 4) & 1) != c) w[m] = f2{0.f, 0.f};   // mask by bit15 = c
        #pragma unroll
        for (int mm = 0; mm < 32; mm += 2)
            gate1q(w[mm], w[mm + 1], uR1[0] + (bsel << 3)); // G11^{bsel}
        apply1q_mg<1, 0, 32>(w, uR1[1]);   // G12..G15
        apply1q_mg<2, 1, 32>(w, uR1[2]);
        apply1q_mg<3, 2, 32>(w, uR1[3]);
        apply1q_mg<4, 3, 32>(w, uR1[4]);
        int k = (c << 1) | j;
        float* d = rvg + ((size_t)(b * 2 + bsel) * 4 + k) * 64;
        #pragma unroll
        for (int m = 0; m < 32; ++m) { d[2 * m] = w[m].x; d[2 * m + 1] = w[m].y; }
    }

    // ---- layer-0 pass A (sparse): SR1 by tid 0 only; full tile written -------------
    {
        f2 a[16];
        #pragma unroll
        for (int j2 = 0; j2 < 16; ++j2) a[j2] = f2{0.f, 0.f};
        if (tid == 0) {
            a[0] = f2{1.f, 0.f};
            apply1q_win<0, 16>(a, uL0[0]);
            apply1q_mg<1, 0, 16>(a, uL0[1]);
            apply1q_mg<2, 1, 16>(a, uL0[2]);
            apply1q_mg<3, 2, 16>(a, uL0[3]);
        }
        #pragma unroll
        for (int j2 = 0; j2 < 16; ++j2) lds[SWZA((tid << 4) | j2)] = a[j2];
    }
    __syncthreads();
    // SR2 (bits 3-6): support requires bits 4-11 == 0 -> only tid < 8
    if (tid < 8) {
        f2 a[16];
        int lo = tid & 7;
        #pragma unroll
        for (int j2 = 0; j2 < 16; ++j2) a[j2] = lds[SWZA(lo | (j2 << 3))];
        apply1q_mg<1, 0, 16>(a, uL0[4]);
        apply1q_mg<2, 1, 16>(a, uL0[5]);
        apply1q_mg<3, 2, 16>(a, uL0[6]);
        #pragma unroll
        for (int j2 = 0; j2 < 16; ++j2) lds[SWZA(lo | (j2 << 3))] = a[j2];
    }
    __syncthreads();
    // SR3 (bits 6-9): support requires bits 7-11 == 0 -> only tid < 64
    if (tid < 64) {
        f2 a[16];
        int lo2 = tid & 63;
        #pragma unroll
        for (int j2 = 0; j2 < 16; ++j2) a[j2] = lds[SWZA(lo2 | (j2 << 6))];
        apply1q_mg<1, 0, 16>(a, uL0[7]);
        apply1q_mg<2, 1, 16>(a, uL0[8]);
        apply1q_mg<3, 2, 16>(a, uL0[9]);
        #pragma unroll
        for (int j2 = 0; j2 < 16; ++j2) lds[SWZA(lo2 | (j2 << 6))] = a[j2];
    }
    __syncthreads();
    // SR4 (bits 8-11): full
    {
        f2 a[16];
        #pragma unroll
        for (int j2 = 0; j2 < 16; ++j2) a[j2] = lds[SWZA(tid | (j2 << 8))];
        apply1q_mg<2, 1, 16>(a, uL0[10]);
        apply1q_mg<3, 2, 16>(a, uL0[11]);
        #pragma unroll
        for (int j2 = 0; j2 < 16; ++j2) lds[SWZA(tid | (j2 << 8))] = a[j2];
    }
    __syncthreads();

    // ---- layer-1 left gates G0..G10 on factor fj, variant vv (in-place, 5 rounds) --
    float g[16];
    f2 a8[8];
    const int jb = fj << 11;
    // R1: t bits 0-2 = r ; t bits 3-10 = tid
    {
        int base = jb | (tid << 3);
        #pragma unroll
        for (int r = 0; r < 8; ++r) a8[r] = lds[SWZA(base | r)];
        if (vv) {
            float c = cs15l0[0], s = cs15l0[1];
            #pragma unroll
            for (int r = 0; r < 8; r += 2) crx_pair(a8[r], a8[r + 1], c, s);
        }
        loadU16(uL1[0], g);  apply1q_win<0, 8>(a8, g);     // G0
        loadU16(uL1[1], g);  apply1q_mg<1, 0, 8>(a8, g);   // G1
        loadU16(uL1[2], g);  apply1q_mg<2, 1, 8>(a8, g);   // G2
        #pragma unroll
        for (int r = 0; r < 8; ++r) lds[SWZA(base | r)] = a8[r];
    }
    __syncthreads();
    // R2: t bits 2-4 = r ; bits 0-1 = tid&3 ; bits 5-10 = tid>>2
    {
        int base = jb | (tid & 3) | ((tid >> 2) << 5);
        #pragma unroll
        for (int r = 0; r < 8; ++r) a8[r] = lds[SWZA(base | (r << 2))];
        loadU16(uL1[3], g);  apply1q_mg<1, 0, 8>(a8, g);   // G3
        loadU16(uL1[4], g);  apply1q_mg<2, 1, 8>(a8, g);   // G4
        #pragma unroll
        for (int r = 0; r < 8; ++r) lds[SWZA(base | (r << 2))] = a8[r];
    }
    __syncthreads();
    // R3: t bits 4-6 = r ; bits 0-3 = tid&15 ; bits 7-10 = tid>>4
    {
        int base = jb | (tid & 15) | ((tid >> 4) << 7);
        #pragma unroll
        for (int r = 0; r < 8; ++r) a8[r] = lds[SWZA(base | (r << 4))];
        loadU16(uL1[5], g);  apply1q_mg<1, 0, 8>(a8, g);   // G5
        loadU16(uL1[6], g);  apply1q_mg<2, 1, 8>(a8, g);   // G6
        #pragma unroll
        for (int r = 0; r < 8; ++r) lds[SWZA(base | (r << 4))] = a8[r];
    }
    __syncthreads();
    // R4: t bits 6-8 = r ; bits 0-5 = tid&63 ; bits 9-10 = tid>>6
    {
        int base = jb | (tid & 63) | ((tid >> 6) << 9);
        #pragma unroll
        for (int r = 0; r < 8; ++r) a8[r] = lds[SWZA(base | (r << 6))];
        loadU16(uL1[7], g);  apply1q_mg<1, 0, 8>(a8, g);   // G7
        loadU16(uL1[8], g);  apply1q_mg<2, 1, 8>(a8, g);   // G8
        #pragma unroll
        for (int r = 0; r < 8; ++r) lds[SWZA(base | (r << 6))] = a8[r];
    }
    __syncthreads();
    // R5: t bits 8-10 = r ; bits 0-7 = tid ; then store A_k
    {
        int base = jb | tid;
        #pragma unroll
        for (int r = 0; r < 8; ++r) a8[r] = lds[SWZA(base | (r << 8))];
        loadU16(uL1[9], g);   apply1q_mg<1, 0, 8>(a8, g);  // G9
        loadU16(uL1[10], g);  apply1q_mg<2, 1, 8>(a8, g);  // G10
        int k = (vv << 1) | fj;
        f2* Ao = Aout + ((size_t)(b * 4 + k) << 11) + tid;
        #pragma unroll
        for (int r = 0; r < 8; ++r) Ao[r << 8] = a8[r];
    }
}

// ---------------- kernel 3: rank-4 expansion + CRX(15,0) + EV (WHT) + fused head ----
// grid: 1024 (b = blk>>3, part = blk&7) ; 256 threads ; t = part*256+tid (bits 0-10)
// Last finishing block per batch computes head + log_softmax (fixed sum order).
__global__ __launch_bounds__(256) void qev(const float* __restrict__ crx2,
                                           const float* __restrict__ rvg,
                                           const f2* __restrict__ Aout,
                                           const float* __restrict__ fcw,
                                           const float* __restrict__ fcb,
                                           float* __restrict__ evp,
                                           int* __restrict__ qcnt,
                                           float* __restrict__ out) {
    __shared__ float rlds[256];
    __shared__ float redP[4][7];
    __shared__ float redQ[4][5];
    __shared__ float evf[16];
    __shared__ float lgf[16];
    __shared__ int lastflag;
    int tid = threadIdx.x;
    int b = blockIdx.x >> 3, part = blockIdx.x & 7;
    int t = part * 256 + tid;
    int bsel = (part >> 2) & 1;          // t bit 10 (block-uniform)

    rlds[tid] = rvg[(size_t)(b * 2 + bsel) * 256 + tid];
    f2 A[4], sA[4];
    #pragma unroll
    for (int k = 0; k < 4; ++k) {
        A[k] = Aout[((size_t)(b * 4 + k) << 11) + t];
        sA[k] = f2{ -A[k].y, A[k].x };
    }
    float c15 = cosf(0.5f * crx2[15]), s15 = sinf(0.5f * crx2[15]);
    __syncthreads();

    f2 a[32];
    #pragma unroll
    for (int m = 0; m < 32; ++m) {
        f2 ac = rlds[0 * 64 + 2 * m] * A[0] + rlds[0 * 64 + 2 * m + 1] * sA[0];
        ac   += rlds[1 * 64 + 2 * m] * A[1] + rlds[1 * 64 + 2 * m + 1] * sA[1];
        ac   += rlds[2 * 64 + 2 * m] * A[2] + rlds[2 * 64 + 2 * m + 1] * sA[2];
        ac   += rlds[3 * 64 + 2 * m] * A[3] + rlds[3 * 64 + 2 * m + 1] * sA[3];
        a[m] = ac;
    }
    {   // layer-1 CRX(15,0): control = m bit 4, target = t bit 0 = lane bit 0
        #pragma unroll
        for (int m = 16; m < 32; ++m) {
            float pr = __shfl_xor(a[m].x, 1);
            float pi = __shfl_xor(a[m].y, 1);
            float nr = c15 * a[m].x + s15 * pi;
            float ni = c15 * a[m].y - s15 * pr;
            a[m].x = nr; a[m].y = ni;
        }
    }

    float P = 0.f, S0 = 0.f, S1 = 0.f, S2 = 0.f, S3 = 0.f, S4 = 0.f;
    #pragma unroll
    for (int m = 0; m < 32; ++m) {
        float pr = a[m].x * a[m].x + a[m].y * a[m].y;
        P += pr;
        S0 += (m & 1)  ? -pr : pr;
        S1 += (m & 2)  ? -pr : pr;
        S2 += (m & 4)  ? -pr : pr;
        S3 += (m & 8)  ? -pr : pr;
        S4 += (m & 16) ? -pr : pr;
    }

    // WHT over 6 lane bits for P; plain butterfly sums for S*
    int lane = tid & 63, wave = tid >> 6;
    #pragma unroll
    for (int o = 1; o < 64; o <<= 1) {
        float tP = __shfl_xor(P, o);
        P = (lane & o) ? (tP - P) : (P + tP);
        S0 += __shfl_xor(S0, o);
        S1 += __shfl_xor(S1, o);
        S2 += __shfl_xor(S2, o);
        S3 += __shfl_xor(S3, o);
        S4 += __shfl_xor(S4, o);
    }
    if ((lane & (lane - 1)) == 0) {       // lanes 0,1,2,4,8,16,32
        int slot = (lane == 0) ? 0 : (31 - __clz((unsigned)lane)) + 1;  // 1..6
        redP[wave][slot] = P;
    }
    if (lane == 0) {
        redQ[wave][0] = S0; redQ[wave][1] = S1; redQ[wave][2] = S2;
        redQ[wave][3] = S3; redQ[wave][4] = S4;
    }
    __syncthreads();
    if (tid < 16) {
        int q = tid;
        float v;
        if (q < 6)       v = redP[0][1+q] + redP[1][1+q] + redP[2][1+q] + redP[3][1+q];
        else if (q == 6) v = redP[0][0] - redP[1][0] + redP[2][0] - redP[3][0]; // t6=wave b0
        else if (q == 7) v = redP[0][0] + redP[1][0] - redP[2][0] - redP[3][0]; // t7=wave b1
        else if (q < 11) {
            v = redP[0][0] + redP[1][0] + redP[2][0] + redP[3][0];
            if ((part >> (q - 8)) & 1) v = -v;                                  // t8..10
        } else           v = redQ[0][q-11] + redQ[1][q-11] + redQ[2][q-11] + redQ[3][q-11];
        evp[(size_t)(b * 8 + part) * 16 + q] = v;
    }
    __threadfence();                     // release this block's slot device-wide
    if (tid == 0) lastflag = (atomicAdd(&qcnt[b], 1) == 7);
    __syncthreads();
    if (lastflag) {                      // last block for batch b: fused head
        __threadfence();                 // acquire all slots
        if (tid < 16) {
            float e = 0.f;
            #pragma unroll
            for (int p2 = 0; p2 < 8; ++p2) e += evp[(size_t)(b * 8 + p2) * 16 + tid];
            evf[tid] = e;
        }
        __syncthreads();
        if (tid < 16) {
            int c = tid;
            float v = fcb[c];
            #pragma unroll
            for (int q = 0; q < 16; ++q) v += evf[q] * fcw[c * 16 + q];
            lgf[c] = v;
        }
        __syncthreads();
        if (tid < 16) {
            float mx = -1e30f;
            #pragma unroll
            for (int c2 = 0; c2 < 16; ++c2) mx = fmaxf(mx, lgf[c2]);
            float se = 0.f;
            #pragma unroll
            for (int c2 = 0; c2 < 16; ++c2) se += expf(lgf[c2] - mx);
            out[b * 16 + tid] = lgf[tid] - (mx + logf(se));
        }
    }
}

// ---------------- launch ----------------
extern "C" void kernel_launch(void* const* d_in, const int* in_sizes, int n_in,
                              void* d_out, int out_size, void* d_ws, size_t ws_size,
                              hipStream_t stream) {
    const float* x    = (const float*)d_in[0];
    const float* cw   = (const float*)d_in[1];
    const float* cb   = (const float*)d_in[2];
    const float* rot1 = (const float*)d_in[3];
    const float* crx1 = (const float*)d_in[4];
    const float* rot2 = (const float*)d_in[5];
    const float* crx2 = (const float*)d_in[6];
    const float* fcw  = (const float*)d_in[7];
    const float* fcb  = (const float*)d_in[8];

    float* ws   = (float*)d_ws;
    float* p    = ws;                      // 4096 floats
    float* rvg  = ws + 4096;               // 128*2*4*64 = 65536 -> ends 69632
    float* evp  = ws + 69632;              // 128*8*16 = 16384 -> ends 86016
    int*   qcnt = (int*)(ws + 86016);      // 128 ints -> ends 86144
    f2*    Aout = (f2*)(ws + 90112);       // 128*4*2048 f2 = 8 MiB

    pool_kernel<<<4096, 256, 0, stream>>>(x, p);
    qfused<<<512, 256, 0, stream>>>(p, cw, cb, rot1, crx1, rot2, crx2,
                                    rvg, Aout, qcnt);
    qev<<<1024, 256, 0, stream>>>(crx2, rvg, Aout, fcw, fcb, evp, qcnt,
                                  (float*)d_out);
}

// Round 12
// 63.150 us; speedup vs baseline: 2.0068x; 2.0068x over previous
//
#include <hip/hip_runtime.h>
#include <hip/hip_bf16.h>

typedef float f2 __attribute__((ext_vector_type(2)));

// ---------------- helpers ----------------

// swizzle for 4096-amp f2 LDS tile: XOR low 4 bits with bits 4-7 (bijective)
#define SWZA(i) ((i) ^ (((i) >> 4) & 15))

// complex 2x2 gate on an amplitude pair; u = {u00r,u00i,u01r,u01i,u10r,u10i,u11r,u11i}
__device__ __forceinline__ void gate1q(f2& a0, f2& a1, const float* u) {
    f2 s0 = { -a0.y, a0.x };
    f2 s1 = { -a1.y, a1.x };
    f2 n0 = u[0]*a0 + u[1]*s0 + u[2]*a1 + u[3]*s1;
    f2 n1 = u[4]*a0 + u[5]*s0 + u[6]*a1 + u[7]*s1;
    a0 = n0; a1 = n1;
}

// RX on the (a0,a1) pair: n0 = c*a0 - i*s*a1 ; n1 = -i*s*a0 + c*a1
__device__ __forceinline__ void crx_pair(f2& a0, f2& a1, float c, float s) {
    f2 t0 = { a0.y, -a0.x };
    f2 t1 = { a1.y, -a1.x };
    f2 n0 = c*a0 + s*t1;
    f2 n1 = c*a1 + s*t0;
    a0 = n0; a1 = n1;
}

// plain 1q gate over W-amp window, target bit K
template<int K, int W>
__device__ __forceinline__ void apply1q_win(f2* a, const float* u) {
    #pragma unroll
    for (int m = 0; m < W / 2; ++m) {
        const int j0 = ((m >> K) << (K + 1)) | (m & ((1 << K) - 1));
        gate1q(a[j0], a[j0 | (1 << K)], u);
    }
}

// merged (U_q then CRX(q-1,q)) : control-selected 2x2. u16 = {U | RX*U}
template<int K, int KC, int W>
__device__ __forceinline__ void apply1q_mg(f2* a, const float* u16) {
    #pragma unroll
    for (int m = 0; m < W / 2; ++m) {
        const int j0 = ((m >> K) << (K + 1)) | (m & ((1 << K) - 1));
        const float* uu = u16 + (((j0 >> KC) & 1) << 3);
        gate1q(a[j0], a[j0 | (1 << K)], uu);
    }
}

__device__ __forceinline__ void loadU16(const float* __restrict__ src, float* u) {
    #pragma unroll
    for (int k = 0; k < 16; ++k) u[k] = src[k];
}

// ---------------- kernel 1: adaptive pool ----------------
__global__ __launch_bounds__(256) void pool_kernel(const float* __restrict__ x,
                                                   float* __restrict__ p) {
    int blk = blockIdx.x;            // b*32 + j
    int b = blk >> 5, j = blk & 31;
    int c = j >> 4, dd = (j >> 2) & 3, hh = j & 3;
    const float4* xb = (const float4*)(x + (((size_t)(b * 2 + c) * 16 + dd * 4) << 12)
                                         + (size_t)hh * 1024);
    int tid = threadIdx.x;
    float sum = 0.f;
    #pragma unroll
    for (int k = 0; k < 4; ++k) {
        int f = k * 256 + tid;
        int r = f >> 4, col = f & 15;
        int off = (r >> 4) * 1024 + (r & 15) * 16 + col;
        float4 v = xb[off];
        sum += v.x + v.y + v.z + v.w;
    }
    #pragma unroll
    for (int o = 1; o < 64; o <<= 1) sum += __shfl_xor(sum, o);
    __shared__ float red[4];
    if ((tid & 63) == 0) red[tid >> 6] = sum;
    __syncthreads();
    if (tid == 0) p[blk] = (red[0] + red[1] + red[2] + red[3]) * (1.0f / 4096.0f);
}

// ---------------- kernel 2: prep + sparse passA + right chains + left gates ---------
// grid = 512: b = blk>>2, vv = (blk>>1)&1, fj = blk&1. 256 threads, ~34 KB LDS.
// Each block produces ONE left factor A_k (k = vv*2+fj), 2048 amps, 8 amps/thread.
__global__ __launch_bounds__(256) void qfused(const float* __restrict__ p,
                                              const float* __restrict__ cw,
                                              const float* __restrict__ cb,
                                              const float* __restrict__ rot1,
                                              const float* __restrict__ crx1,
                                              const float* __restrict__ rot2,
                                              const float* __restrict__ crx2,
                                              float* __restrict__ rvg,
                                              f2* __restrict__ Aout,
                                              float* __restrict__ ev) {
    __shared__ f2 lds[4096];
    __shared__ float pp[32];
    __shared__ float uL0[12][16];   // layer-0 merged U0..U11
    __shared__ float uB0[4][16];    // layer-0 merged U12..U15
    __shared__ float uL1[11][16];   // layer-1 merged U0..U10
    __shared__ float uR1[5][16];    // layer-1 merged U11..U15
    __shared__ float cs15l0[2];     // layer-0 CRX(15,0) c,s
    int bid = blockIdx.x;
    int b = bid >> 2, vv = (bid >> 1) & 1, fj = bid & 1;
    int tid = threadIdx.x;

    if (tid < 32) pp[tid] = p[b * 32 + tid];
    __syncthreads();
    // prep: 32 threads, one per (q, l)
    if (tid < 32) {
        int q = tid & 15, l = tid >> 4;
        float f = cb[q];
        #pragma unroll
        for (int jj = 0; jj < 32; ++jj) f += pp[jj] * cw[q * 32 + jj];
        float cr = cosf(0.5f * f), sr = sinf(0.5f * f);
        const float* rw = (l == 0 ? rot1 : rot2) + q * 3;
        float phi = rw[0], th = rw[1], om = rw[2];
        float ct = cosf(0.5f * th), st = sinf(0.5f * th);
        float aa = 0.5f * (phi + om), dd = 0.5f * (phi - om);
        float ca = cosf(aa), sa = sinf(aa), cd = cosf(dd), sd = sinf(dd);
        float R00r =  ct * ca, R00i = -ct * sa;
        float R01r = -st * cd, R01i = -st * sd;
        float R10r =  st * cd, R10i = -st * sd;
        float R11r =  ct * ca, R11i =  ct * sa;
        float u0 = cr * R00r + sr * R01i;
        float u1 = cr * R00i - sr * R01r;
        float u2 = cr * R01r + sr * R00i;
        float u3 = cr * R01i - sr * R00r;
        float u4 = cr * R10r + sr * R11i;
        float u5 = cr * R10i - sr * R11r;
        float u6 = cr * R11r + sr * R10i;
        float u7 = cr * R11i - sr * R10r;
        float g[16];
        g[0] = u0; g[1] = u1; g[2] = u2; g[3] = u3;
        g[4] = u4; g[5] = u5; g[6] = u6; g[7] = u7;
        if (q >= 1) {
            float thc = (l == 0 ? crx1 : crx2)[q - 1];
            float c2 = cosf(0.5f * thc), s2 = sinf(0.5f * thc);
            g[8]  = c2*u0 + s2*u5;  g[9]  = c2*u1 - s2*u4;
            g[10] = c2*u2 + s2*u7;  g[11] = c2*u3 - s2*u6;
            g[12] = c2*u4 + s2*u1;  g[13] = c2*u5 - s2*u0;
            g[14] = c2*u6 + s2*u3;  g[15] = c2*u7 - s2*u2;
        } else {
            #pragma unroll
            for (int k = 0; k < 8; ++k) g[8 + k] = g[k];
        }
        float* s = (l == 0) ? ((q < 12) ? uL0[q] : uB0[q - 12])
                            : ((q < 11) ? uL1[q] : uR1[q - 11]);
        #pragma unroll
        for (int k = 0; k < 16; ++k) s[k] = g[k];
        if (l == 0 && q == 15) {
            cs15l0[0] = cosf(0.5f * crx1[15]);
            cs15l0[1] = sinf(0.5f * crx1[15]);
        }
    }
    // zero ev for this batch (one block per batch)
    if ((bid & 3) == 0 && tid >= 64 && tid < 80) ev[b * 16 + (tid - 64)] = 0.f;
    __syncthreads();

    // ---- right chains: one block per batch, 8 wave-3 threads, one per (j,c,bsel) ---
    if ((bid & 3) == 0 && tid >= 192 && tid < 200) {
        int idx = tid - 192;
        int j = idx & 1, c = (idx >> 1) & 1, bsel = (idx >> 2) & 1;
        f2 w[32];
        #pragma unroll
        for (int m = 0; m < 32; ++m) w[m] = f2{0.f, 0.f};
        w[j] = f2{1.f, 0.f};
        apply1q_mg<1, 0, 32>(w, uB0[0]);   // L0: U12 + CRX(11,12)
        apply1q_mg<2, 1, 32>(w, uB0[1]);
        apply1q_mg<3, 2, 32>(w, uB0[2]);
        apply1q_mg<4, 3, 32>(w, uB0[3]);
        #pragma unroll
        for (int m = 0; m < 32; ++m)
            if (((m >> 4) & 1) != c) w[m] = f2{0.f, 0.f};   // mask by bit15 = c
        #pragma unroll
        for (int mm = 0; mm < 32; mm += 2)
            gate1q(w[mm], w[mm + 1], uR1[0] + (bsel << 3)); // G11^{bsel}
        apply1q_mg<1, 0, 32>(w, uR1[1]);   // G12..G15
        apply1q_mg<2, 1, 32>(w, uR1[2]);
        apply1q_mg<3, 2, 32>(w, uR1[3]);
        apply1q_mg<4, 3, 32>(w, uR1[4]);
        int k = (c << 1) | j;
        float* d = rvg + ((size_t)(b * 2 + bsel) * 4 + k) * 64;
        #pragma unroll
        for (int m = 0; m < 32; ++m) { d[2 * m] = w[m].x; d[2 * m + 1] = w[m].y; }
    }

    // ---- layer-0 pass A (sparse): SR1 by tid 0 only; full tile written -------------
    {
        f2 a[16];
        #pragma unroll
        for (int j2 = 0; j2 < 16; ++j2) a[j2] = f2{0.f, 0.f};
        if (tid == 0) {
            a[0] = f2{1.f, 0.f};
            apply1q_win<0, 16>(a, uL0[0]);
            apply1q_mg<1, 0, 16>(a, uL0[1]);
            apply1q_mg<2, 1, 16>(a, uL0[2]);
            apply1q_mg<3, 2, 16>(a, uL0[3]);
        }
        #pragma unroll
        for (int j2 = 0; j2 < 16; ++j2) lds[SWZA((tid << 4) | j2)] = a[j2];
    }
    __syncthreads();
    // SR2 (bits 3-6): support requires bits 4-11 == 0 -> only tid < 8
    if (tid < 8) {
        f2 a[16];
        int lo = tid & 7;
        #pragma unroll
        for (int j2 = 0; j2 < 16; ++j2) a[j2] = lds[SWZA(lo | (j2 << 3))];
        apply1q_mg<1, 0, 16>(a, uL0[4]);
        apply1q_mg<2, 1, 16>(a, uL0[5]);
        apply1q_mg<3, 2, 16>(a, uL0[6]);
        #pragma unroll
        for (int j2 = 0; j2 < 16; ++j2) lds[SWZA(lo | (j2 << 3))] = a[j2];
    }
    __syncthreads();
    // SR3 (bits 6-9): support requires bits 7-11 == 0 -> only tid < 64
    if (tid < 64) {
        f2 a[16];
        int lo2 = tid & 63;
        #pragma unroll
        for (int j2 = 0; j2 < 16; ++j2) a[j2] = lds[SWZA(lo2 | (j2 << 6))];
        apply1q_mg<1, 0, 16>(a, uL0[7]);
        apply1q_mg<2, 1, 16>(a, uL0[8]);
        apply1q_mg<3, 2, 16>(a, uL0[9]);
        #pragma unroll
        for (int j2 = 0; j2 < 16; ++j2) lds[SWZA(lo2 | (j2 << 6))] = a[j2];
    }
    __syncthreads();
    // SR4 (bits 8-11): full
    {
        f2 a[16];
        #pragma unroll
        for (int j2 = 0; j2 < 16; ++j2) a[j2] = lds[SWZA(tid | (j2 << 8))];
        apply1q_mg<2, 1, 16>(a, uL0[10]);
        apply1q_mg<3, 2, 16>(a, uL0[11]);
        #pragma unroll
        for (int j2 = 0; j2 < 16; ++j2) lds[SWZA(tid | (j2 << 8))] = a[j2];
    }
    __syncthreads();

    // ---- layer-1 left gates G0..G10 on factor fj, variant vv (in-place, 5 rounds) --
    float g[16];
    f2 a8[8];
    const int jb = fj << 11;
    // R1: t bits 0-2 = r ; t bits 3-10 = tid
    {
        int base = jb | (tid << 3);
        #pragma unroll
        for (int r = 0; r < 8; ++r) a8[r] = lds[SWZA(base | r)];
        if (vv) {
            float c = cs15l0[0], s = cs15l0[1];
            #pragma unroll
            for (int r = 0; r < 8; r += 2) crx_pair(a8[r], a8[r + 1], c, s);
        }
        loadU16(uL1[0], g);  apply1q_win<0, 8>(a8, g);     // G0
        loadU16(uL1[1], g);  apply1q_mg<1, 0, 8>(a8, g);   // G1
        loadU16(uL1[2], g);  apply1q_mg<2, 1, 8>(a8, g);   // G2
        #pragma unroll
        for (int r = 0; r < 8; ++r) lds[SWZA(base | r)] = a8[r];
    }
    __syncthreads();
    // R2: t bits 2-4 = r ; bits 0-1 = tid&3 ; bits 5-10 = tid>>2
    {
        int base = jb | (tid & 3) | ((tid >> 2) << 5);
        #pragma unroll
        for (int r = 0; r < 8; ++r) a8[r] = lds[SWZA(base | (r << 2))];
        loadU16(uL1[3], g);  apply1q_mg<1, 0, 8>(a8, g);   // G3
        loadU16(uL1[4], g);  apply1q_mg<2, 1, 8>(a8, g);   // G4
        #pragma unroll
        for (int r = 0; r < 8; ++r) lds[SWZA(base | (r << 2))] = a8[r];
    }
    __syncthreads();
    // R3: t bits 4-6 = r ; bits 0-3 = tid&15 ; bits 7-10 = tid>>4
    {
        int base = jb | (tid & 15) | ((tid >> 4) << 7);
        #pragma unroll
        for (int r = 0; r < 8; ++r) a8[r] = lds[SWZA(base | (r << 4))];
        loadU16(uL1[5], g);  apply1q_mg<1, 0, 8>(a8, g);   // G5
        loadU16(uL1[6], g);  apply1q_mg<2, 1, 8>(a8, g);   // G6
        #pragma unroll
        for (int r = 0; r < 8; ++r) lds[SWZA(base | (r << 4))] = a8[r];
    }
    __syncthreads();
    // R4: t bits 6-8 = r ; bits 0-5 = tid&63 ; bits 9-10 = tid>>6
    {
        int base = jb | (tid & 63) | ((tid >> 6) << 9);
        #pragma unroll
        for (int r = 0; r < 8; ++r) a8[r] = lds[SWZA(base | (r << 6))];
        loadU16(uL1[7], g);  apply1q_mg<1, 0, 8>(a8, g);   // G7
        loadU16(uL1[8], g);  apply1q_mg<2, 1, 8>(a8, g);   // G8
        #pragma unroll
        for (int r = 0; r < 8; ++r) lds[SWZA(base | (r << 6))] = a8[r];
    }
    __syncthreads();
    // R5: t bits 8-10 = r ; bits 0-7 = tid ; then store A_k
    {
        int base = jb | tid;
        #pragma unroll
        for (int r = 0; r < 8; ++r) a8[r] = lds[SWZA(base | (r << 8))];
        loadU16(uL1[9], g);   apply1q_mg<1, 0, 8>(a8, g);  // G9
        loadU16(uL1[10], g);  apply1q_mg<2, 1, 8>(a8, g);  // G10
        int k = (vv << 1) | fj;
        f2* Ao = Aout + ((size_t)(b * 4 + k) << 11) + tid;
        #pragma unroll
        for (int r = 0; r < 8; ++r) Ao[r << 8] = a8[r];
    }
}

// ---------------- kernel 3: rank-4 expansion + CRX(15,0) + EV reduce (WHT) ----------
// grid: 1024 (b = blk>>3, part = blk&7) ; 256 threads ; t = part*256+tid (bits 0-10)
// R9-proven structure: rb from global (L2-hot), atomicAdd to ev, no fences.
__global__ __launch_bounds__(256) void qev(const float* __restrict__ crx2,
                                           const float* __restrict__ rvg,
                                           const f2* __restrict__ Aout,
                                           float* __restrict__ ev) {
    int tid = threadIdx.x;
    int b = blockIdx.x >> 3, part = blockIdx.x & 7;
    int t = part * 256 + tid;
    int bsel = (part >> 2) & 1;          // t bit 10 (block-uniform)

    f2 A[4], sA[4];
    #pragma unroll
    for (int k = 0; k < 4; ++k) {
        A[k] = Aout[((size_t)(b * 4 + k) << 11) + t];
        sA[k] = f2{ -A[k].y, A[k].x };
    }
    const float* rb = rvg + (size_t)(b * 2 + bsel) * 256;   // [k][2m]

    f2 a[32];
    #pragma unroll
    for (int m = 0; m < 32; ++m) {
        f2 ac = rb[0 * 64 + 2 * m] * A[0] + rb[0 * 64 + 2 * m + 1] * sA[0];
        ac   += rb[1 * 64 + 2 * m] * A[1] + rb[1 * 64 + 2 * m + 1] * sA[1];
        ac   += rb[2 * 64 + 2 * m] * A[2] + rb[2 * 64 + 2 * m + 1] * sA[2];
        ac   += rb[3 * 64 + 2 * m] * A[3] + rb[3 * 64 + 2 * m + 1] * sA[3];
        a[m] = ac;
    }

    {   // layer-1 CRX(15,0): control = m bit 4, target = t bit 0 = lane bit 0
        float c15 = cosf(0.5f * crx2[15]), s15 = sinf(0.5f * crx2[15]);
        #pragma unroll
        for (int m = 16; m < 32; ++m) {
            float pr = __shfl_xor(a[m].x, 1);
            float pi = __shfl_xor(a[m].y, 1);
            float nr = c15 * a[m].x + s15 * pi;
            float ni = c15 * a[m].y - s15 * pr;
            a[m].x = nr; a[m].y = ni;
        }
    }

    float P = 0.f, S0 = 0.f, S1 = 0.f, S2 = 0.f, S3 = 0.f, S4 = 0.f;
    #pragma unroll
    for (int m = 0; m < 32; ++m) {
        float pr = a[m].x * a[m].x + a[m].y * a[m].y;
        P += pr;
        S0 += (m & 1)  ? -pr : pr;
        S1 += (m & 2)  ? -pr : pr;
        S2 += (m & 4)  ? -pr : pr;
        S3 += (m & 8)  ? -pr : pr;
        S4 += (m & 16) ? -pr : pr;
    }

    // WHT over 6 lane bits for P; plain butterfly sums for S*
    int lane = tid & 63, wave = tid >> 6;
    #pragma unroll
    for (int o = 1; o < 64; o <<= 1) {
        float tP = __shfl_xor(P, o);
        P = (lane & o) ? (tP - P) : (P + tP);
        S0 += __shfl_xor(S0, o);
        S1 += __shfl_xor(S1, o);
        S2 += __shfl_xor(S2, o);
        S3 += __shfl_xor(S3, o);
        S4 += __shfl_xor(S4, o);
    }
    __shared__ float redP[4][7];
    __shared__ float redQ[4][5];
    if ((lane & (lane - 1)) == 0) {       // lanes 0,1,2,4,8,16,32
        int slot = (lane == 0) ? 0 : (31 - __clz((unsigned)lane)) + 1;  // 1..6
        redP[wave][slot] = P;
    }
    if (lane == 0) {
        redQ[wave][0] = S0; redQ[wave][1] = S1; redQ[wave][2] = S2;
        redQ[wave][3] = S3; redQ[wave][4] = S4;
    }
    __syncthreads();
    if (tid < 16) {
        int q = tid;
        float v;
        if (q < 6)       v = redP[0][1+q] + redP[1][1+q] + redP[2][1+q] + redP[3][1+q];
        else if (q == 6) v = redP[0][0] - redP[1][0] + redP[2][0] - redP[3][0]; // t6=wave b0
        else if (q == 7) v = redP[0][0] + redP[1][0] - redP[2][0] - redP[3][0]; // t7=wave b1
        else if (q < 11) {
            v = redP[0][0] + redP[1][0] + redP[2][0] + redP[3][0];
            if ((part >> (q - 8)) & 1) v = -v;                                  // t8..10
        } else           v = redQ[0][q-11] + redQ[1][q-11] + redQ[2][q-11] + redQ[3][q-11];
        atomicAdd(&ev[b * 16 + q], v);
    }
}

// ---------------- kernel 4: head + log_softmax ----------------
__global__ __launch_bounds__(128) void head_kernel(const float* __restrict__ ev,
                                                   const float* __restrict__ fcw,
                                                   const float* __restrict__ fcb,
                                                   float* __restrict__ out) {
    int b = threadIdx.x;
    if (b >= 128) return;
    float e[16];
    #pragma unroll
    for (int q = 0; q < 16; ++q) e[q] = ev[b * 16 + q];
    float lg[16];
    float mx = -1e30f;
    #pragma unroll
    for (int c = 0; c < 16; ++c) {
        float v = fcb[c];
        #pragma unroll
        for (int q = 0; q < 16; ++q) v += e[q] * fcw[c * 16 + q];
        lg[c] = v;
        mx = fmaxf(mx, v);
    }
    float se = 0.f;
    #pragma unroll
    for (int c = 0; c < 16; ++c) se += expf(lg[c] - mx);
    float lse = mx + logf(se);
    #pragma unroll
    for (int c = 0; c < 16; ++c) out[b * 16 + c] = lg[c] - lse;
}

// ---------------- launch ----------------
extern "C" void kernel_launch(void* const* d_in, const int* in_sizes, int n_in,
                              void* d_out, int out_size, void* d_ws, size_t ws_size,
                              hipStream_t stream) {
    const float* x    = (const float*)d_in[0];
    const float* cw   = (const float*)d_in[1];
    const float* cb   = (const float*)d_in[2];
    const float* rot1 = (const float*)d_in[3];
    const float* crx1 = (const float*)d_in[4];
    const float* rot2 = (const float*)d_in[5];
    const float* crx2 = (const float*)d_in[6];
    const float* fcw  = (const float*)d_in[7];
    const float* fcb  = (const float*)d_in[8];

    float* ws   = (float*)d_ws;
    float* p    = ws;                      // 4096 floats
    float* rvg  = ws + 4096;               // 128*2*4*64 = 65536 -> ends 69632
    float* ev   = ws + 69632;              // 2048 -> ends 71680
    f2*    Aout = (f2*)(ws + 73728);       // 128*4*2048 f2 = 8 MiB

    pool_kernel<<<4096, 256, 0, stream>>>(x, p);
    qfused<<<512, 256, 0, stream>>>(p, cw, cb, rot1, crx1, rot2, crx2,
                                    rvg, Aout, ev);
    qev<<<1024, 256, 0, stream>>>(crx2, rvg, Aout, ev);
    head_kernel<<<1, 128, 0, stream>>>(ev, fcw, fcb, (float*)d_out);
}

// Round 13
// 37.047 us; speedup vs baseline: 3.4208x; 1.7046x over previous
//
#include <hip/hip_runtime.h>
#include <hip/hip_bf16.h>

typedef float f2 __attribute__((ext_vector_type(2)));

// ---------------- shuffle-gate: merged 2x2 gate, amp-per-lane ----------------
// u: 16 floats {U | M1}; kt = target lane-bit; kc = control lane-bit (<0: plain, use u[0..7])
__device__ __forceinline__ f2 sgate(f2 a, int lane, int kt, int kc, const float* u) {
    f2 p;
    p.x = __shfl_xor(a.x, 1 << kt);
    p.y = __shfl_xor(a.y, 1 << kt);
    const float* uu = u + ((kc >= 0 && ((lane >> kc) & 1)) ? 8 : 0);
    int bit = (lane >> kt) & 1;
    float cAr = bit ? uu[6] : uu[0], cAi = bit ? uu[7] : uu[1];
    float cPr = bit ? uu[4] : uu[2], cPi = bit ? uu[5] : uu[3];
    f2 r;
    r.x = cAr * a.x - cAi * a.y + cPr * p.x - cPi * p.y;
    r.y = cAr * a.y + cAi * a.x + cPr * p.y + cPi * p.x;
    return r;
}

// ---------------- kernel 1: adaptive pool ----------------
__global__ __launch_bounds__(256) void pool_kernel(const float* __restrict__ x,
                                                   float* __restrict__ p) {
    int blk = blockIdx.x;            // b*32 + j
    int b = blk >> 5, j = blk & 31;
    int c = j >> 4, dd = (j >> 2) & 3, hh = j & 3;
    const float4* xb = (const float4*)(x + (((size_t)(b * 2 + c) * 16 + dd * 4) << 12)
                                         + (size_t)hh * 1024);
    int tid = threadIdx.x;
    float sum = 0.f;
    #pragma unroll
    for (int k = 0; k < 4; ++k) {
        int f = k * 256 + tid;
        int r = f >> 4, col = f & 15;
        int off = (r >> 4) * 1024 + (r & 15) * 16 + col;
        float4 v = xb[off];
        sum += v.x + v.y + v.z + v.w;
    }
    #pragma unroll
    for (int o = 1; o < 64; o <<= 1) sum += __shfl_xor(sum, o);
    __shared__ float red[4];
    if ((tid & 63) == 0) red[tid >> 6] = sum;
    __syncthreads();
    if (tid == 0) p[blk] = (red[0] + red[1] + red[2] + red[3]) * (1.0f / 4096.0f);
}

// ---------------- kernel 2: factor preamble + rank-16 expansion + EV (WHT) ----------
// grid: 1024 (b = blk>>3, part = blk&7) ; 256 threads.
// Preamble (per block, LDS only): merged gate matrices; stage A: ell(bits0-5),
// Rr_p(bits6-11), W_j(bits11-15); stage B: B_{c,p}(64), C_{p,j,p2}(32), R_{c,j,bsel}(32).
// Main: A_{c,j}(t) = sum_p B_{c,p}(t&63) * C_{p,j,t5}(t>>6); m-expansion via R;
// layer-1 CRX(15,0) via shfl; P/S reduce (WHT); store evp[b][part][16].
__global__ __launch_bounds__(256) void qev(const float* __restrict__ p,
                                           const float* __restrict__ cw,
                                           const float* __restrict__ cb,
                                           const float* __restrict__ rot1,
                                           const float* __restrict__ crx1,
                                           const float* __restrict__ rot2,
                                           const float* __restrict__ crx2,
                                           float* __restrict__ evp) {
    __shared__ float pp[32];
    __shared__ float uM[32][16];     // [l*16+q] merged {U | RX(crx[q-1])U}
    __shared__ float cs15[4];        // [l0 c,s | l1 c,s] for CRX(15,0)
    __shared__ f2 ell[64];
    __shared__ f2 Rr[2][64];
    __shared__ f2 Wl[2][32];
    __shared__ f2 Btab[4][64];       // [c*2+p][x]
    __shared__ f2 Ctab[8][32];       // [(p*2+j)*2+p2][y]
    __shared__ float Rtab[2][4][64]; // [bsel][c*2+j][2m+ri]
    __shared__ float redP[4][7];
    __shared__ float redQ[4][5];
    int tid = threadIdx.x;
    int b = blockIdx.x >> 3, part = blockIdx.x & 7;

    if (tid < 32) pp[tid] = p[b * 32 + tid];
    __syncthreads();

    // ---- merged gate matrices: 32 threads, one per (q, l) ----
    if (tid < 32) {
        int q = tid & 15, l = tid >> 4;
        float f = cb[q];
        #pragma unroll
        for (int jj = 0; jj < 32; ++jj) f += pp[jj] * cw[q * 32 + jj];
        float cr = cosf(0.5f * f), sr = sinf(0.5f * f);
        const float* rw = (l == 0 ? rot1 : rot2) + q * 3;
        float phi = rw[0], th = rw[1], om = rw[2];
        float ct = cosf(0.5f * th), st = sinf(0.5f * th);
        float aa = 0.5f * (phi + om), dd = 0.5f * (phi - om);
        float ca = cosf(aa), sa = sinf(aa), cd = cosf(dd), sd = sinf(dd);
        float R00r =  ct * ca, R00i = -ct * sa;
        float R01r = -st * cd, R01i = -st * sd;
        float R10r =  st * cd, R10i = -st * sd;
        float R11r =  ct * ca, R11i =  ct * sa;
        float u0 = cr * R00r + sr * R01i;
        float u1 = cr * R00i - sr * R01r;
        float u2 = cr * R01r + sr * R00i;
        float u3 = cr * R01i - sr * R00r;
        float u4 = cr * R10r + sr * R11i;
        float u5 = cr * R10i - sr * R11r;
        float u6 = cr * R11r + sr * R10i;
        float u7 = cr * R11i - sr * R10r;
        float g[16];
        g[0] = u0; g[1] = u1; g[2] = u2; g[3] = u3;
        g[4] = u4; g[5] = u5; g[6] = u6; g[7] = u7;
        if (q >= 1) {
            float thc = (l == 0 ? crx1 : crx2)[q - 1];
            float c2 = cosf(0.5f * thc), s2 = sinf(0.5f * thc);
            g[8]  = c2*u0 + s2*u5;  g[9]  = c2*u1 - s2*u4;
            g[10] = c2*u2 + s2*u7;  g[11] = c2*u3 - s2*u6;
            g[12] = c2*u4 + s2*u1;  g[13] = c2*u5 - s2*u0;
            g[14] = c2*u6 + s2*u3;  g[15] = c2*u7 - s2*u2;
        } else {
            #pragma unroll
            for (int k = 0; k < 8; ++k) g[8 + k] = g[k];
        }
        float* s = uM[l * 16 + q];
        #pragma unroll
        for (int k = 0; k < 16; ++k) s[k] = g[k];
        if (q == 15) {
            float th2 = (l == 0 ? crx1 : crx2)[15];
            cs15[l * 2]     = cosf(0.5f * th2);
            cs15[l * 2 + 1] = sinf(0.5f * th2);
        }
    }
    __syncthreads();

    int wv = tid >> 6, lane = tid & 63;

    // ---- stage A: ell (wave 0), Rr_p (waves 1,2), W_j (wave 3 halves) ----
    if (wv == 0) {
        f2 a = (lane == 0) ? f2{1.f, 0.f} : f2{0.f, 0.f};
        a = sgate(a, lane, 0, -1, uM[0]);                 // L0 G0
        #pragma unroll
        for (int q = 1; q <= 5; ++q) a = sgate(a, lane, q, q - 1, uM[q]);
        ell[lane] = a;
    } else if (wv <= 2) {
        int pidx = wv - 1;
        const float* m6 = uM[6] + pidx * 8;               // M_p = L0-G6 variant
        f2 a = f2{0.f, 0.f};
        if (lane == 0) a = f2{m6[0], m6[1]};
        if (lane == 1) a = f2{m6[4], m6[5]};
        #pragma unroll
        for (int q = 7; q <= 11; ++q) a = sgate(a, lane, q - 6, q - 7, uM[q]);
        Rr[pidx][lane] = a;
    } else {
        int j = lane >> 5, lm = lane & 31;
        f2 a = (lm == j) ? f2{1.f, 0.f} : f2{0.f, 0.f};   // e_j at bit11 (m bit 0)
        #pragma unroll
        for (int q = 12; q <= 15; ++q) a = sgate(a, lane, q - 11, q - 12, uM[q]);
        Wl[j][lm] = a;
    }
    __syncthreads();

    // ---- stage B: B (4x64), C (8x32), R (8x32) — each wave does one of each ----
    {   // B_{c,p}: c = wv>>1, p = wv&1
        int c = wv >> 1, pb = wv & 1;
        f2 a = ell[lane];
        if (((lane >> 5) & 1) != pb) a = f2{0.f, 0.f};    // P_p on bit 5
        if (c) {                                          // RX0(L0 crx15) on bit 0
            f2 pr; pr.x = __shfl_xor(a.x, 1); pr.y = __shfl_xor(a.y, 1);
            f2 n = cs15[0] * a;
            n.x += cs15[1] * pr.y; n.y -= cs15[1] * pr.x;
            a = n;
        }
        a = sgate(a, lane, 0, -1, uM[16]);                // L1 G0
        #pragma unroll
        for (int q = 1; q <= 5; ++q) a = sgate(a, lane, q, q - 1, uM[16 + q]);
        Btab[wv][lane] = a;
    }
    {   // C_{p,j,p2}: p = wv>>1, p2 = wv&1, halves j
        int pidx = wv >> 1, p2 = wv & 1, j = lane >> 5, lm = lane & 31;
        f2 a = Rr[pidx][(j << 5) | lm];                   // restrict bit11 = j
        a = sgate(a, lane, 0, -1, uM[16 + 6] + p2 * 8);   // M_{p2} = L1-G6 variant on bit6
        #pragma unroll
        for (int q = 7; q <= 10; ++q) a = sgate(a, lane, q - 6, q - 7, uM[16 + q]);
        Ctab[(pidx * 2 + j) * 2 + p2][lm] = a;
    }
    {   // R_{c,j}^{bsel}: c = wv>>1, bsel = wv&1, halves j
        int c = wv >> 1, bsel = wv & 1, j = lane >> 5, lm = lane & 31;
        f2 a = Wl[j][lm];
        if (((lm >> 4) & 1) != c) a = f2{0.f, 0.f};       // mask bit15 = c
        a = sgate(a, lane, 0, -1, uM[16 + 11] + bsel * 8);  // L1 G11^{bsel}
        #pragma unroll
        for (int q = 12; q <= 15; ++q) a = sgate(a, lane, q - 11, q - 12, uM[16 + q]);
        Rtab[bsel][c * 2 + j][2 * lm]     = a.x;
        Rtab[bsel][c * 2 + j][2 * lm + 1] = a.y;
    }
    __syncthreads();

    // ---- main: rank contraction + CRX(15,0) + EV reduce ----
    int t = part * 256 + tid;
    int x5 = (lane >> 5) & 1;
    int y = (t >> 6) & 31;               // wave-uniform
    int bsel = (part >> 2) & 1;          // t bit 10 (block-uniform)

    f2 Bv[2][2], Cv[2][2];
    #pragma unroll
    for (int c = 0; c < 2; ++c)
        #pragma unroll
        for (int pq = 0; pq < 2; ++pq) Bv[c][pq] = Btab[c * 2 + pq][lane];
    #pragma unroll
    for (int pq = 0; pq < 2; ++pq)
        #pragma unroll
        for (int j = 0; j < 2; ++j) Cv[pq][j] = Ctab[(pq * 2 + j) * 2 + x5][y];

    f2 A[4], sA[4];
    #pragma unroll
    for (int c = 0; c < 2; ++c)
        #pragma unroll
        for (int j = 0; j < 2; ++j) {
            f2 acc = f2{0.f, 0.f};
            #pragma unroll
            for (int pq = 0; pq < 2; ++pq) {
                f2 Bb = Bv[c][pq], Cc = Cv[pq][j];
                acc.x += Bb.x * Cc.x - Bb.y * Cc.y;
                acc.y += Bb.x * Cc.y + Bb.y * Cc.x;
            }
            A[c * 2 + j] = acc;
            sA[c * 2 + j] = f2{-acc.y, acc.x};
        }

    const float* rb = &Rtab[bsel][0][0];   // [k][2m]
    f2 a[32];
    #pragma unroll
    for (int m = 0; m < 32; ++m) {
        f2 ac = rb[0 * 64 + 2 * m] * A[0] + rb[0 * 64 + 2 * m + 1] * sA[0];
        ac   += rb[1 * 64 + 2 * m] * A[1] + rb[1 * 64 + 2 * m + 1] * sA[1];
        ac   += rb[2 * 64 + 2 * m] * A[2] + rb[2 * 64 + 2 * m + 1] * sA[2];
        ac   += rb[3 * 64 + 2 * m] * A[3] + rb[3 * 64 + 2 * m + 1] * sA[3];
        a[m] = ac;
    }

    {   // layer-1 CRX(15,0): control = m bit 4, target = t bit 0 = lane bit 0
        float c15 = cs15[2], s15 = cs15[3];
        #pragma unroll
        for (int m = 16; m < 32; ++m) {
            float pr = __shfl_xor(a[m].x, 1);
            float pi = __shfl_xor(a[m].y, 1);
            float nr = c15 * a[m].x + s15 * pi;
            float ni = c15 * a[m].y - s15 * pr;
            a[m].x = nr; a[m].y = ni;
        }
    }

    float P = 0.f, S0 = 0.f, S1 = 0.f, S2 = 0.f, S3 = 0.f, S4 = 0.f;
    #pragma unroll
    for (int m = 0; m < 32; ++m) {
        float pr = a[m].x * a[m].x + a[m].y * a[m].y;
        P += pr;
        S0 += (m & 1)  ? -pr : pr;
        S1 += (m & 2)  ? -pr : pr;
        S2 += (m & 4)  ? -pr : pr;
        S3 += (m & 8)  ? -pr : pr;
        S4 += (m & 16) ? -pr : pr;
    }

    // WHT over 6 lane bits for P; plain butterfly sums for S*
    #pragma unroll
    for (int o = 1; o < 64; o <<= 1) {
        float tP = __shfl_xor(P, o);
        P = (lane & o) ? (tP - P) : (P + tP);
        S0 += __shfl_xor(S0, o);
        S1 += __shfl_xor(S1, o);
        S2 += __shfl_xor(S2, o);
        S3 += __shfl_xor(S3, o);
        S4 += __shfl_xor(S4, o);
    }
    if ((lane & (lane - 1)) == 0) {       // lanes 0,1,2,4,8,16,32
        int slot = (lane == 0) ? 0 : (31 - __clz((unsigned)lane)) + 1;  // 1..6
        redP[wv][slot] = P;
    }
    if (lane == 0) {
        redQ[wv][0] = S0; redQ[wv][1] = S1; redQ[wv][2] = S2;
        redQ[wv][3] = S3; redQ[wv][4] = S4;
    }
    __syncthreads();
    if (tid < 16) {
        int q = tid;
        float v;
        if (q < 6)       v = redP[0][1+q] + redP[1][1+q] + redP[2][1+q] + redP[3][1+q];
        else if (q == 6) v = redP[0][0] - redP[1][0] + redP[2][0] - redP[3][0]; // t6=wave b0
        else if (q == 7) v = redP[0][0] + redP[1][0] - redP[2][0] - redP[3][0]; // t7=wave b1
        else if (q < 11) {
            v = redP[0][0] + redP[1][0] + redP[2][0] + redP[3][0];
            if ((part >> (q - 8)) & 1) v = -v;                                  // t8..10
        } else           v = redQ[0][q-11] + redQ[1][q-11] + redQ[2][q-11] + redQ[3][q-11];
        evp[(size_t)(b * 8 + part) * 16 + q] = v;
    }
}

// ---------------- kernel 3: head + log_softmax (sums evp parts) ----------------
__global__ __launch_bounds__(128) void head_kernel(const float* __restrict__ evp,
                                                   const float* __restrict__ fcw,
                                                   const float* __restrict__ fcb,
                                                   float* __restrict__ out) {
    int b = threadIdx.x;
    if (b >= 128) return;
    float e[16];
    #pragma unroll
    for (int q = 0; q < 16; ++q) {
        float s = 0.f;
        #pragma unroll
        for (int pt = 0; pt < 8; ++pt) s += evp[(size_t)(b * 8 + pt) * 16 + q];
        e[q] = s;
    }
    float lg[16];
    float mx = -1e30f;
    #pragma unroll
    for (int c = 0; c < 16; ++c) {
        float v = fcb[c];
        #pragma unroll
        for (int q = 0; q < 16; ++q) v += e[q] * fcw[c * 16 + q];
        lg[c] = v;
        mx = fmaxf(mx, v);
    }
    float se = 0.f;
    #pragma unroll
    for (int c = 0; c < 16; ++c) se += expf(lg[c] - mx);
    float lse = mx + logf(se);
    #pragma unroll
    for (int c = 0; c < 16; ++c) out[b * 16 + c] = lg[c] - lse;
}

// ---------------- launch ----------------
extern "C" void kernel_launch(void* const* d_in, const int* in_sizes, int n_in,
                              void* d_out, int out_size, void* d_ws, size_t ws_size,
                              hipStream_t stream) {
    const float* x    = (const float*)d_in[0];
    const float* cw   = (const float*)d_in[1];
    const float* cb   = (const float*)d_in[2];
    const float* rot1 = (const float*)d_in[3];
    const float* crx1 = (const float*)d_in[4];
    const float* rot2 = (const float*)d_in[5];
    const float* crx2 = (const float*)d_in[6];
    const float* fcw  = (const float*)d_in[7];
    const float* fcb  = (const float*)d_in[8];

    float* ws  = (float*)d_ws;
    float* p   = ws;               // 4096 floats
    float* evp = ws + 4096;        // 128*8*16 = 16384 floats

    pool_kernel<<<4096, 256, 0, stream>>>(x, p);
    qev<<<1024, 256, 0, stream>>>(p, cw, cb, rot1, crx1, rot2, crx2, evp);
    head_kernel<<<1, 128, 0, stream>>>(evp, fcw, fcb, (float*)d_out);
}

// Round 14
// 33.377 us; speedup vs baseline: 3.7969x; 1.1099x over previous
//
#include <hip/hip_runtime.h>
#include <hip/hip_bf16.h>

typedef float f2 __attribute__((ext_vector_type(2)));

// ---------------- shuffle-gate: merged 2x2 gate, amp-per-lane ----------------
// u: 16 floats {U | M1}; kt = target lane-bit; kc = control lane-bit (<0: plain)
__device__ __forceinline__ f2 sgate(f2 a, int lane, int kt, int kc, const float* u) {
    f2 p;
    p.x = __shfl_xor(a.x, 1 << kt);
    p.y = __shfl_xor(a.y, 1 << kt);
    const float* uu = u + ((kc >= 0 && ((lane >> kc) & 1)) ? 8 : 0);
    int bit = (lane >> kt) & 1;
    float cAr = bit ? uu[6] : uu[0], cAi = bit ? uu[7] : uu[1];
    float cPr = bit ? uu[4] : uu[2], cPi = bit ? uu[5] : uu[3];
    f2 r;
    r.x = cAr * a.x - cAi * a.y + cPr * p.x - cPi * p.y;
    r.y = cAr * a.y + cAi * a.x + cPr * p.y + cPi * p.x;
    return r;
}

__device__ __forceinline__ f2 cmul(f2 A, f2 B) {
    return f2{A.x * B.x - A.y * B.y, A.x * B.y + A.y * B.x};
}
// x * conj(y)
__device__ __forceinline__ f2 cmulc(f2 x, f2 y) {
    return f2{x.x * y.x + x.y * y.y, x.y * y.x - x.x * y.y};
}

// ---------------- kernel 1: adaptive pool ----------------
__global__ __launch_bounds__(256) void pool_kernel(const float* __restrict__ x,
                                                   float* __restrict__ p) {
    int blk = blockIdx.x;            // b*32 + j
    int b = blk >> 5, j = blk & 31;
    int c = j >> 4, dd = (j >> 2) & 3, hh = j & 3;
    const float4* xb = (const float4*)(x + (((size_t)(b * 2 + c) * 16 + dd * 4) << 12)
                                         + (size_t)hh * 1024);
    int tid = threadIdx.x;
    float sum = 0.f;
    #pragma unroll
    for (int k = 0; k < 4; ++k) {
        int f = k * 256 + tid;
        int r = f >> 4, col = f & 15;
        int off = (r >> 4) * 1024 + (r & 15) * 16 + col;
        float4 v = xb[off];
        sum += v.x + v.y + v.z + v.w;
    }
    #pragma unroll
    for (int o = 1; o < 64; o <<= 1) sum += __shfl_xor(sum, o);
    __shared__ float red[4];
    if ((tid & 63) == 0) red[tid >> 6] = sum;
    __syncthreads();
    if (tid == 0) p[blk] = (red[0] + red[1] + red[2] + red[3]) * (1.0f / 4096.0f);
}

// ---------------- kernel 2: prep — tables per batch (runs ONCE per batch) -----------
// grid = 128 (one block per batch), 256 threads.
// Produces per batch (tabs + b*1536 floats):
//   [0..511]    Btab[c*2+p][x]   (f2)   left factor over t bits 0-5
//   [512..1023] Ctab[(p*2+j)*2+p2][y] (f2)  left factor over t bits 6-10
//   [1024..1407] Ht[bsel][pt][k][k2] (f2)  6 Gram mats (pt: P, m-bit0..4)
//   [1408..1471] Dt[bsel][k][k2] (f2)     = E_lo + (c^2-s^2) E_hi  (pattern P)
//   [1472..1535] Et[bsel][k][k2] (f2)     = c*s*E_hi               (pattern P)
__global__ __launch_bounds__(256) void prep(const float* __restrict__ p,
                                            const float* __restrict__ cw,
                                            const float* __restrict__ cb,
                                            const float* __restrict__ rot1,
                                            const float* __restrict__ crx1,
                                            const float* __restrict__ rot2,
                                            const float* __restrict__ crx2,
                                            float* __restrict__ tabs) {
    __shared__ float pp[32];
    __shared__ float uM[32][16];     // [l*16+q] merged {U | RX(crx[q-1])U}
    __shared__ float cs15[4];        // [l0 c,s | l1 c,s] for CRX(15,0)
    __shared__ f2 ell[64];
    __shared__ f2 Rr[2][64];
    __shared__ f2 Wl[2][32];
    __shared__ f2 Btab[4][64];       // [c*2+p][x]
    __shared__ f2 Ctab[8][32];       // [(p*2+j)*2+p2][y]
    __shared__ float Rtab[2][4][64]; // [bsel][c*2+j][2m+ri]
    int tid = threadIdx.x;
    int b = blockIdx.x;

    if (tid < 32) pp[tid] = p[b * 32 + tid];
    __syncthreads();

    // ---- merged gate matrices: 32 threads, one per (q, l) ----
    if (tid < 32) {
        int q = tid & 15, l = tid >> 4;
        float f = cb[q];
        #pragma unroll
        for (int jj = 0; jj < 32; ++jj) f += pp[jj] * cw[q * 32 + jj];
        float cr = cosf(0.5f * f), sr = sinf(0.5f * f);
        const float* rw = (l == 0 ? rot1 : rot2) + q * 3;
        float phi = rw[0], th = rw[1], om = rw[2];
        float ct = cosf(0.5f * th), st = sinf(0.5f * th);
        float aa = 0.5f * (phi + om), dd = 0.5f * (phi - om);
        float ca = cosf(aa), sa = sinf(aa), cd = cosf(dd), sd = sinf(dd);
        float R00r =  ct * ca, R00i = -ct * sa;
        float R01r = -st * cd, R01i = -st * sd;
        float R10r =  st * cd, R10i = -st * sd;
        float R11r =  ct * ca, R11i =  ct * sa;
        float u0 = cr * R00r + sr * R01i;
        float u1 = cr * R00i - sr * R01r;
        float u2 = cr * R01r + sr * R00i;
        float u3 = cr * R01i - sr * R00r;
        float u4 = cr * R10r + sr * R11i;
        float u5 = cr * R10i - sr * R11r;
        float u6 = cr * R11r + sr * R10i;
        float u7 = cr * R11i - sr * R10r;
        float g[16];
        g[0] = u0; g[1] = u1; g[2] = u2; g[3] = u3;
        g[4] = u4; g[5] = u5; g[6] = u6; g[7] = u7;
        if (q >= 1) {
            float thc = (l == 0 ? crx1 : crx2)[q - 1];
            float c2 = cosf(0.5f * thc), s2 = sinf(0.5f * thc);
            g[8]  = c2*u0 + s2*u5;  g[9]  = c2*u1 - s2*u4;
            g[10] = c2*u2 + s2*u7;  g[11] = c2*u3 - s2*u6;
            g[12] = c2*u4 + s2*u1;  g[13] = c2*u5 - s2*u0;
            g[14] = c2*u6 + s2*u3;  g[15] = c2*u7 - s2*u2;
        } else {
            #pragma unroll
            for (int k = 0; k < 8; ++k) g[8 + k] = g[k];
        }
        float* s = uM[l * 16 + q];
        #pragma unroll
        for (int k = 0; k < 16; ++k) s[k] = g[k];
        if (q == 15) {
            float th2 = (l == 0 ? crx1 : crx2)[15];
            cs15[l * 2]     = cosf(0.5f * th2);
            cs15[l * 2 + 1] = sinf(0.5f * th2);
        }
    }
    __syncthreads();

    int wv = tid >> 6, lane = tid & 63;

    // ---- stage A: ell (wave 0), Rr_p (waves 1,2), W_j (wave 3 halves) ----
    if (wv == 0) {
        f2 a = (lane == 0) ? f2{1.f, 0.f} : f2{0.f, 0.f};
        a = sgate(a, lane, 0, -1, uM[0]);                 // L0 G0
        #pragma unroll
        for (int q = 1; q <= 5; ++q) a = sgate(a, lane, q, q - 1, uM[q]);
        ell[lane] = a;
    } else if (wv <= 2) {
        int pidx = wv - 1;
        const float* m6 = uM[6] + pidx * 8;               // M_p = L0-G6 variant
        f2 a = f2{0.f, 0.f};
        if (lane == 0) a = f2{m6[0], m6[1]};
        if (lane == 1) a = f2{m6[4], m6[5]};
        #pragma unroll
        for (int q = 7; q <= 11; ++q) a = sgate(a, lane, q - 6, q - 7, uM[q]);
        Rr[pidx][lane] = a;
    } else {
        int j = lane >> 5, lm = lane & 31;
        f2 a = (lm == j) ? f2{1.f, 0.f} : f2{0.f, 0.f};   // e_j at bit11 (m bit 0)
        #pragma unroll
        for (int q = 12; q <= 15; ++q) a = sgate(a, lane, q - 11, q - 12, uM[q]);
        Wl[j][lm] = a;
    }
    __syncthreads();

    // ---- stage B: B (4x64), C (8x32), R (8x32) — each wave does one of each ----
    {   // B_{c,p}: c = wv>>1, p = wv&1
        int c = wv >> 1, pb = wv & 1;
        f2 a = ell[lane];
        if (((lane >> 5) & 1) != pb) a = f2{0.f, 0.f};    // P_p on bit 5
        if (c) {                                          // RX0(L0 crx15) on bit 0
            f2 pr; pr.x = __shfl_xor(a.x, 1); pr.y = __shfl_xor(a.y, 1);
            f2 n = cs15[0] * a;
            n.x += cs15[1] * pr.y; n.y -= cs15[1] * pr.x;
            a = n;
        }
        a = sgate(a, lane, 0, -1, uM[16]);                // L1 G0
        #pragma unroll
        for (int q = 1; q <= 5; ++q) a = sgate(a, lane, q, q - 1, uM[16 + q]);
        Btab[wv][lane] = a;
    }
    {   // C_{p,j,p2}: p = wv>>1, p2 = wv&1, halves j
        int pidx = wv >> 1, p2 = wv & 1, j = lane >> 5, lm = lane & 31;
        f2 a = Rr[pidx][(j << 5) | lm];                   // restrict bit11 = j
        a = sgate(a, lane, 0, -1, uM[16 + 6] + p2 * 8);   // M_{p2} = L1-G6 variant
        #pragma unroll
        for (int q = 7; q <= 10; ++q) a = sgate(a, lane, q - 6, q - 7, uM[16 + q]);
        Ctab[(pidx * 2 + j) * 2 + p2][lm] = a;
    }
    {   // R_{c,j}^{bsel}: c = wv>>1, bsel = wv&1, halves j
        int c = wv >> 1, bsel = wv & 1, j = lane >> 5, lm = lane & 31;
        f2 a = Wl[j][lm];
        if (((lm >> 4) & 1) != c) a = f2{0.f, 0.f};       // mask bit15 = c
        a = sgate(a, lane, 0, -1, uM[16 + 11] + bsel * 8);  // L1 G11^{bsel}
        #pragma unroll
        for (int q = 12; q <= 15; ++q) a = sgate(a, lane, q - 11, q - 12, uM[16 + q]);
        Rtab[bsel][c * 2 + j][2 * lm]     = a.x;
        Rtab[bsel][c * 2 + j][2 * lm + 1] = a.y;
    }
    __syncthreads();

    // ---- write Btab / Ctab ----
    float* tb = tabs + (size_t)b * 1536;
    {
        f2 v = ((const f2*)Btab)[tid];              // 256 f2
        tb[2 * tid] = v.x; tb[2 * tid + 1] = v.y;
        f2 w = ((const f2*)Ctab)[tid];              // 256 f2
        tb[512 + 2 * tid] = w.x; tb[512 + 2 * tid + 1] = w.y;
    }

    // ---- Gram matrices: 192 threads, one per (bsel, pattern, k, k2) ----
    if (tid < 192) {
        int bsel = tid / 96, rem = tid % 96, pt = rem >> 4, kk = rem & 15;
        int k = kk >> 2, k2 = kk & 3;
        float c15 = cs15[2], s15 = cs15[3];
        f2 Elo = f2{0.f, 0.f}, Ehi = f2{0.f, 0.f};
        #pragma unroll
        for (int m = 0; m < 32; ++m) {
            float rk = Rtab[bsel][k][2 * m],  ik = Rtab[bsel][k][2 * m + 1];
            float rp = Rtab[bsel][k2][2 * m], ip = Rtab[bsel][k2][2 * m + 1];
            float sg = (pt == 0) ? 1.f : (((m >> (pt - 1)) & 1) ? -1.f : 1.f);
            float wr = sg * (rk * rp + ik * ip);     // R_k * conj(R_k2)
            float wi = sg * (ik * rp - rk * ip);
            if (m < 16) { Elo.x += wr; Elo.y += wi; }
            else        { Ehi.x += wr; Ehi.y += wi; }
        }
        tb[1024 + ((bsel * 6 + pt) * 16 + kk) * 2]     = Elo.x + Ehi.x;
        tb[1024 + ((bsel * 6 + pt) * 16 + kk) * 2 + 1] = Elo.y + Ehi.y;
        if (pt == 0) {
            float ccss = c15 * c15 - s15 * s15;
            tb[1408 + (bsel * 16 + kk) * 2]     = Elo.x + ccss * Ehi.x;
            tb[1408 + (bsel * 16 + kk) * 2 + 1] = Elo.y + ccss * Ehi.y;
            float cs = c15 * s15;
            tb[1472 + (bsel * 16 + kk) * 2]     = cs * Ehi.x;
            tb[1472 + (bsel * 16 + kk) * 2 + 1] = cs * Ehi.y;
        }
    }
}

// ---------------- kernel 3: per-t-pair quadratic forms + EV reduce (WHT) -----------
// grid: 512 (b = blk>>2, part = blk&3) ; 256 threads ; tau = part*256+tid (t bits 1-10)
__global__ __launch_bounds__(256) void qev(const float* __restrict__ tabs,
                                           float* __restrict__ evp) {
    __shared__ float sB[512], sC[512], sH[192], sD[32], sE[32];
    __shared__ float redP[4][7];
    __shared__ float redQ[4][6];
    int tid = threadIdx.x;
    int b = blockIdx.x >> 2, part = blockIdx.x & 3;
    int bsel = (part >> 1) & 1;
    const float* tb = tabs + (size_t)b * 1536;

    sB[tid] = tb[tid];             sB[tid + 256] = tb[tid + 256];
    sC[tid] = tb[512 + tid];       sC[tid + 256] = tb[768 + tid];
    if (tid < 192) sH[tid] = tb[1024 + bsel * 192 + tid];
    else if (tid < 224) sD[tid - 192] = tb[1408 + bsel * 32 + (tid - 192)];
    else               sE[tid - 224] = tb[1472 + bsel * 32 + (tid - 224)];
    __syncthreads();

    int lane = tid & 63, wv = tid >> 6;
    int x0 = 2 * (tid & 31), x1 = x0 + 1;
    int x5 = (tid >> 4) & 1;
    int y = part * 8 + (tid >> 5);

    f2 B0[2][2], B1[2][2], Cv[2][2];
    #pragma unroll
    for (int c = 0; c < 2; ++c)
        #pragma unroll
        for (int pq = 0; pq < 2; ++pq) {
            int bi = (c * 2 + pq) * 64;
            B0[c][pq] = f2{sB[(bi + x0) * 2], sB[(bi + x0) * 2 + 1]};
            B1[c][pq] = f2{sB[(bi + x1) * 2], sB[(bi + x1) * 2 + 1]};
        }
    #pragma unroll
    for (int pq = 0; pq < 2; ++pq)
        #pragma unroll
        for (int j = 0; j < 2; ++j) {
            int ci = ((pq * 2 + j) * 2 + x5) * 32;
            Cv[pq][j] = f2{sC[(ci + y) * 2], sC[(ci + y) * 2 + 1]};
        }

    // rank contraction at t0=2tau (a) and t1=2tau+1 (bb); k = c*2+j
    f2 a[4], bb[4];
    #pragma unroll
    for (int c = 0; c < 2; ++c)
        #pragma unroll
        for (int j = 0; j < 2; ++j) {
            f2 s0 = cmul(B0[c][0], Cv[0][j]);
            f2 s1 = cmul(B0[c][1], Cv[1][j]);
            a[c * 2 + j] = f2{s0.x + s1.x, s0.y + s1.y};
            f2 t0 = cmul(B1[c][0], Cv[0][j]);
            f2 t1 = cmul(B1[c][1], Cv[1][j]);
            bb[c * 2 + j] = f2{t0.x + t1.x, t0.y + t1.y};
        }

    // Hermitian products
    float sum_d[4], dif_d[4];
    #pragma unroll
    for (int k = 0; k < 4; ++k) {
        float pa = a[k].x * a[k].x + a[k].y * a[k].y;
        float pb = bb[k].x * bb[k].x + bb[k].y * bb[k].y;
        sum_d[k] = pa + pb;
        dif_d[k] = pa - pb;
    }
    f2 wS[6], wD[6];
    {
        int pi = 0;
        #pragma unroll
        for (int k = 0; k < 4; ++k)
            #pragma unroll
            for (int k2 = k + 1; k2 < 4; ++k2) {
                f2 u = cmulc(a[k], a[k2]);
                f2 v = cmulc(bb[k], bb[k2]);
                wS[pi] = f2{u.x + v.x, u.y + v.y};
                wD[pi] = f2{u.x - v.x, u.y - v.y};
                ++pi;
            }
    }

    // 6 sum-forms (P, m-bit0..4)
    float F[6];
    #pragma unroll
    for (int pt = 0; pt < 6; ++pt) {
        const float* Hk = sH + pt * 32;
        float f = 0.f;
        #pragma unroll
        for (int k = 0; k < 4; ++k) f += Hk[(k * 4 + k) * 2] * sum_d[k];
        int pi = 0;
        #pragma unroll
        for (int k = 0; k < 4; ++k)
            #pragma unroll
            for (int k2 = k + 1; k2 < 4; ++k2) {
                float hr = Hk[(k * 4 + k2) * 2], hi = Hk[(k * 4 + k2) * 2 + 1];
                f += 2.f * (hr * wS[pi].x - hi * wS[pi].y);
                ++pi;
            }
        F[pt] = f;
    }
    // q=0 form: Q(a,D)-Q(b,D) - 4*Im(sum E[k][k2] a_k conj(b_k2))
    float Pd;
    {
        float f = 0.f;
        #pragma unroll
        for (int k = 0; k < 4; ++k) f += sD[(k * 4 + k) * 2] * dif_d[k];
        int pi = 0;
        #pragma unroll
        for (int k = 0; k < 4; ++k)
            #pragma unroll
            for (int k2 = k + 1; k2 < 4; ++k2) {
                float dr = sD[(k * 4 + k2) * 2], di = sD[(k * 4 + k2) * 2 + 1];
                f += 2.f * (dr * wD[pi].x - di * wD[pi].y);
                ++pi;
            }
        f2 z = f2{0.f, 0.f};
        #pragma unroll
        for (int k = 0; k < 4; ++k) {
            f2 v = f2{0.f, 0.f};
            #pragma unroll
            for (int k2 = 0; k2 < 4; ++k2) {
                float er = sE[(k * 4 + k2) * 2], ei = sE[(k * 4 + k2) * 2 + 1];
                v.x += er * bb[k2].x + ei * bb[k2].y;    // E * conj(b)
                v.y += ei * bb[k2].x - er * bb[k2].y;
            }
            z.x += a[k].x * v.x - a[k].y * v.y;
            z.y += a[k].x * v.y + a[k].y * v.x;
        }
        Pd = f - 4.f * z.y;
    }

    // WHT over 6 lane bits for P; plain butterflies for Pd, S0..S4
    float P = F[0], S0 = F[1], S1 = F[2], S2 = F[3], S3 = F[4], S4 = F[5];
    #pragma unroll
    for (int o = 1; o < 64; o <<= 1) {
        float tP = __shfl_xor(P, o);
        P = (lane & o) ? (tP - P) : (P + tP);
        Pd += __shfl_xor(Pd, o);
        S0 += __shfl_xor(S0, o);
        S1 += __shfl_xor(S1, o);
        S2 += __shfl_xor(S2, o);
        S3 += __shfl_xor(S3, o);
        S4 += __shfl_xor(S4, o);
    }
    if ((lane & (lane - 1)) == 0) {       // lanes 0,1,2,4,8,16,32
        int slot = (lane == 0) ? 0 : (31 - __clz((unsigned)lane)) + 1;  // 1..6
        redP[wv][slot] = P;
    }
    if (lane == 0) {
        redQ[wv][0] = Pd;
        redQ[wv][1] = S0; redQ[wv][2] = S1; redQ[wv][3] = S2;
        redQ[wv][4] = S3; redQ[wv][5] = S4;
    }
    __syncthreads();
    if (tid < 16) {
        int q = tid;
        float v;
        if (q == 0)      v = redQ[0][0] + redQ[1][0] + redQ[2][0] + redQ[3][0];
        else if (q < 7)  v = redP[0][q] + redP[1][q] + redP[2][q] + redP[3][q];
        else if (q == 7) v = redP[0][0] - redP[1][0] + redP[2][0] - redP[3][0]; // tau b6
        else if (q == 8) v = redP[0][0] + redP[1][0] - redP[2][0] - redP[3][0]; // tau b7
        else if (q < 11) {
            v = redP[0][0] + redP[1][0] + redP[2][0] + redP[3][0];
            if ((part >> (q - 9)) & 1) v = -v;                                   // tau b8,b9
        } else           v = redQ[0][q-10] + redQ[1][q-10] + redQ[2][q-10] + redQ[3][q-10];
        evp[(size_t)(b * 4 + part) * 16 + q] = v;
    }
}

// ---------------- kernel 4: head + log_softmax (sums evp parts) ----------------
__global__ __launch_bounds__(128) void head_kernel(const float* __restrict__ evp,
                                                   const float* __restrict__ fcw,
                                                   const float* __restrict__ fcb,
                                                   float* __restrict__ out) {
    int b = threadIdx.x;
    if (b >= 128) return;
    float e[16];
    #pragma unroll
    for (int q = 0; q < 16; ++q) {
        float s = 0.f;
        #pragma unroll
        for (int pt = 0; pt < 4; ++pt) s += evp[(size_t)(b * 4 + pt) * 16 + q];
        e[q] = s;
    }
    float lg[16];
    float mx = -1e30f;
    #pragma unroll
    for (int c = 0; c < 16; ++c) {
        float v = fcb[c];
        #pragma unroll
        for (int q = 0; q < 16; ++q) v += e[q] * fcw[c * 16 + q];
        lg[c] = v;
        mx = fmaxf(mx, v);
    }
    float se = 0.f;
    #pragma unroll
    for (int c = 0; c < 16; ++c) se += expf(lg[c] - mx);
    float lse = mx + logf(se);
    #pragma unroll
    for (int c = 0; c < 16; ++c) out[b * 16 + c] = lg[c] - lse;
}

// ---------------- launch ----------------
extern "C" void kernel_launch(void* const* d_in, const int* in_sizes, int n_in,
                              void* d_out, int out_size, void* d_ws, size_t ws_size,
                              hipStream_t stream) {
    const float* x    = (const float*)d_in[0];
    const float* cw   = (const float*)d_in[1];
    const float* cb   = (const float*)d_in[2];
    const float* rot1 = (const float*)d_in[3];
    const float* crx1 = (const float*)d_in[4];
    const float* rot2 = (const float*)d_in[5];
    const float* crx2 = (const float*)d_in[6];
    const float* fcw  = (const float*)d_in[7];
    const float* fcb  = (const float*)d_in[8];

    float* ws   = (float*)d_ws;
    float* p    = ws;                  // 4096 floats
    float* tabs = ws + 4096;           // 128*1536 = 196608 -> ends 200704
    float* evp  = ws + 200704;         // 128*4*16 = 8192 -> ends 208896

    pool_kernel<<<4096, 256, 0, stream>>>(x, p);
    prep<<<128, 256, 0, stream>>>(p, cw, cb, rot1, crx1, rot2, crx2, tabs);
    qev<<<512, 256, 0, stream>>>(tabs, evp);
    head_kernel<<<1, 128, 0, stream>>>(evp, fcw, fcb, (float*)d_out);
}

// Round 15
// 30.908 us; speedup vs baseline: 4.1003x; 1.0799x over previous
//
#include <hip/hip_runtime.h>
#include <hip/hip_bf16.h>

typedef float f2 __attribute__((ext_vector_type(2)));

// ---------------- shuffle-gate: merged 2x2 gate, amp-per-lane ----------------
// u: 16 floats {U | M1}; kt = target lane-bit; kc = control lane-bit (<0: plain)
__device__ __forceinline__ f2 sgate(f2 a, int lane, int kt, int kc, const float* u) {
    f2 p;
    p.x = __shfl_xor(a.x, 1 << kt);
    p.y = __shfl_xor(a.y, 1 << kt);
    const float* uu = u + ((kc >= 0 && ((lane >> kc) & 1)) ? 8 : 0);
    int bit = (lane >> kt) & 1;
    float cAr = bit ? uu[6] : uu[0], cAi = bit ? uu[7] : uu[1];
    float cPr = bit ? uu[4] : uu[2], cPi = bit ? uu[5] : uu[3];
    f2 r;
    r.x = cAr * a.x - cAi * a.y + cPr * p.x - cPi * p.y;
    r.y = cAr * a.y + cAi * a.x + cPr * p.y + cPi * p.x;
    return r;
}

__device__ __forceinline__ f2 cmul(f2 A, f2 B) {
    return f2{A.x * B.x - A.y * B.y, A.x * B.y + A.y * B.x};
}
// x * conj(y)
__device__ __forceinline__ f2 cmulc(f2 x, f2 y) {
    return f2{x.x * y.x + x.y * y.y, x.y * y.x - x.x * y.y};
}

// ---------------- kernel 1: adaptive pool ----------------
__global__ __launch_bounds__(256) void pool_kernel(const float* __restrict__ x,
                                                   float* __restrict__ p) {
    int blk = blockIdx.x;            // b*32 + j
    int b = blk >> 5, j = blk & 31;
    int c = j >> 4, dd = (j >> 2) & 3, hh = j & 3;
    const float4* xb = (const float4*)(x + (((size_t)(b * 2 + c) * 16 + dd * 4) << 12)
                                         + (size_t)hh * 1024);
    int tid = threadIdx.x;
    float sum = 0.f;
    #pragma unroll
    for (int k = 0; k < 4; ++k) {
        int f = k * 256 + tid;
        int r = f >> 4, col = f & 15;
        int off = (r >> 4) * 1024 + (r & 15) * 16 + col;
        float4 v = xb[off];
        sum += v.x + v.y + v.z + v.w;
    }
    #pragma unroll
    for (int o = 1; o < 64; o <<= 1) sum += __shfl_xor(sum, o);
    __shared__ float red[4];
    if ((tid & 63) == 0) red[tid >> 6] = sum;
    __syncthreads();
    if (tid == 0) p[blk] = (red[0] + red[1] + red[2] + red[3]) * (1.0f / 4096.0f);
}

// ---------------- kernel 2: prep + quadratic forms + EV + head, per batch -----------
// grid = 128 (one block per batch), 256 threads. All tables LDS-resident.
__global__ __launch_bounds__(256) void qfin(const float* __restrict__ p,
                                            const float* __restrict__ cw,
                                            const float* __restrict__ cb,
                                            const float* __restrict__ rot1,
                                            const float* __restrict__ crx1,
                                            const float* __restrict__ rot2,
                                            const float* __restrict__ crx2,
                                            const float* __restrict__ fcw,
                                            const float* __restrict__ fcb,
                                            float* __restrict__ out) {
    __shared__ float pp[32];
    __shared__ float uM[32][16];     // [l*16+q] merged {U | RX(crx[q-1])U}
    __shared__ float cs15[4];        // [l0 c,s | l1 c,s] for CRX(15,0)
    __shared__ f2 ell[64];
    __shared__ f2 Rr[2][64];
    __shared__ f2 Wl[2][32];
    __shared__ f2 Btab[4][64];       // [c*2+p][x]
    __shared__ f2 Ctab[8][32];       // [(p*2+j)*2+p2][y]
    __shared__ float Rtab[2][4][64]; // [bsel][c*2+j][2m+ri]
    __shared__ float sH[2][6][32];   // Gram mats (pt: P, m-bit0..4), f2-flattened
    __shared__ float sD[2][32];
    __shared__ float sE[2][32];
    __shared__ float redP[4][7];
    __shared__ float redQ[4][8];     // Pd, P9, P10, S0..S4
    __shared__ float evf[16];
    __shared__ float lgf[16];
    int tid = threadIdx.x;
    int b = blockIdx.x;

    if (tid < 32) pp[tid] = p[b * 32 + tid];
    __syncthreads();

    // ---- merged gate matrices: 32 threads, one per (q, l) ----
    if (tid < 32) {
        int q = tid & 15, l = tid >> 4;
        float f = cb[q];
        #pragma unroll
        for (int jj = 0; jj < 32; ++jj) f += pp[jj] * cw[q * 32 + jj];
        float cr = cosf(0.5f * f), sr = sinf(0.5f * f);
        const float* rw = (l == 0 ? rot1 : rot2) + q * 3;
        float phi = rw[0], th = rw[1], om = rw[2];
        float ct = cosf(0.5f * th), st = sinf(0.5f * th);
        float aa = 0.5f * (phi + om), dd = 0.5f * (phi - om);
        float ca = cosf(aa), sa = sinf(aa), cd = cosf(dd), sd = sinf(dd);
        float R00r =  ct * ca, R00i = -ct * sa;
        float R01r = -st * cd, R01i = -st * sd;
        float R10r =  st * cd, R10i = -st * sd;
        float R11r =  ct * ca, R11i =  ct * sa;
        float u0 = cr * R00r + sr * R01i;
        float u1 = cr * R00i - sr * R01r;
        float u2 = cr * R01r + sr * R00i;
        float u3 = cr * R01i - sr * R00r;
        float u4 = cr * R10r + sr * R11i;
        float u5 = cr * R10i - sr * R11r;
        float u6 = cr * R11r + sr * R10i;
        float u7 = cr * R11i - sr * R10r;
        float g[16];
        g[0] = u0; g[1] = u1; g[2] = u2; g[3] = u3;
        g[4] = u4; g[5] = u5; g[6] = u6; g[7] = u7;
        if (q >= 1) {
            float thc = (l == 0 ? crx1 : crx2)[q - 1];
            float c2 = cosf(0.5f * thc), s2 = sinf(0.5f * thc);
            g[8]  = c2*u0 + s2*u5;  g[9]  = c2*u1 - s2*u4;
            g[10] = c2*u2 + s2*u7;  g[11] = c2*u3 - s2*u6;
            g[12] = c2*u4 + s2*u1;  g[13] = c2*u5 - s2*u0;
            g[14] = c2*u6 + s2*u3;  g[15] = c2*u7 - s2*u2;
        } else {
            #pragma unroll
            for (int k = 0; k < 8; ++k) g[8 + k] = g[k];
        }
        float* s = uM[l * 16 + q];
        #pragma unroll
        for (int k = 0; k < 16; ++k) s[k] = g[k];
        if (q == 15) {
            float th2 = (l == 0 ? crx1 : crx2)[15];
            cs15[l * 2]     = cosf(0.5f * th2);
            cs15[l * 2 + 1] = sinf(0.5f * th2);
        }
    }
    __syncthreads();

    int wv = tid >> 6, lane = tid & 63;

    // ---- stage A: ell (wave 0), Rr_p (waves 1,2), W_j (wave 3 halves) ----
    if (wv == 0) {
        f2 a = (lane == 0) ? f2{1.f, 0.f} : f2{0.f, 0.f};
        a = sgate(a, lane, 0, -1, uM[0]);                 // L0 G0
        #pragma unroll
        for (int q = 1; q <= 5; ++q) a = sgate(a, lane, q, q - 1, uM[q]);
        ell[lane] = a;
    } else if (wv <= 2) {
        int pidx = wv - 1;
        const float* m6 = uM[6] + pidx * 8;               // M_p = L0-G6 variant
        f2 a = f2{0.f, 0.f};
        if (lane == 0) a = f2{m6[0], m6[1]};
        if (lane == 1) a = f2{m6[4], m6[5]};
        #pragma unroll
        for (int q = 7; q <= 11; ++q) a = sgate(a, lane, q - 6, q - 7, uM[q]);
        Rr[pidx][lane] = a;
    } else {
        int j = lane >> 5, lm = lane & 31;
        f2 a = (lm == j) ? f2{1.f, 0.f} : f2{0.f, 0.f};   // e_j at bit11 (m bit 0)
        #pragma unroll
        for (int q = 12; q <= 15; ++q) a = sgate(a, lane, q - 11, q - 12, uM[q]);
        Wl[j][lm] = a;
    }
    __syncthreads();

    // ---- stage B: B (4x64), C (8x32), R (8x32) — each wave does one of each ----
    {   // B_{c,p}: c = wv>>1, p = wv&1
        int c = wv >> 1, pb = wv & 1;
        f2 a = ell[lane];
        if (((lane >> 5) & 1) != pb) a = f2{0.f, 0.f};    // P_p on bit 5
        if (c) {                                          // RX0(L0 crx15) on bit 0
            f2 pr; pr.x = __shfl_xor(a.x, 1); pr.y = __shfl_xor(a.y, 1);
            f2 n = cs15[0] * a;
            n.x += cs15[1] * pr.y; n.y -= cs15[1] * pr.x;
            a = n;
        }
        a = sgate(a, lane, 0, -1, uM[16]);                // L1 G0
        #pragma unroll
        for (int q = 1; q <= 5; ++q) a = sgate(a, lane, q, q - 1, uM[16 + q]);
        Btab[wv][lane] = a;
    }
    {   // C_{p,j,p2}: p = wv>>1, p2 = wv&1, halves j
        int pidx = wv >> 1, p2 = wv & 1, j = lane >> 5, lm = lane & 31;
        f2 a = Rr[pidx][(j << 5) | lm];                   // restrict bit11 = j
        a = sgate(a, lane, 0, -1, uM[16 + 6] + p2 * 8);   // M_{p2} = L1-G6 variant
        #pragma unroll
        for (int q = 7; q <= 10; ++q) a = sgate(a, lane, q - 6, q - 7, uM[16 + q]);
        Ctab[(pidx * 2 + j) * 2 + p2][lm] = a;
    }
    {   // R_{c,j}^{bsel}: c = wv>>1, bsel = wv&1, halves j
        int c = wv >> 1, bsel = wv & 1, j = lane >> 5, lm = lane & 31;
        f2 a = Wl[j][lm];
        if (((lm >> 4) & 1) != c) a = f2{0.f, 0.f};       // mask bit15 = c
        a = sgate(a, lane, 0, -1, uM[16 + 11] + bsel * 8);  // L1 G11^{bsel}
        #pragma unroll
        for (int q = 12; q <= 15; ++q) a = sgate(a, lane, q - 11, q - 12, uM[16 + q]);
        Rtab[bsel][c * 2 + j][2 * lm]     = a.x;
        Rtab[bsel][c * 2 + j][2 * lm + 1] = a.y;
    }
    __syncthreads();

    // ---- Gram matrices: 192 threads, one per (bsel, pattern, k, k2) -> LDS ----
    if (tid < 192) {
        int bsel = tid / 96, rem = tid % 96, pt = rem >> 4, kk = rem & 15;
        int k = kk >> 2, k2 = kk & 3;
        float c15 = cs15[2], s15 = cs15[3];
        f2 Elo = f2{0.f, 0.f}, Ehi = f2{0.f, 0.f};
        #pragma unroll
        for (int m = 0; m < 32; ++m) {
            float rk = Rtab[bsel][k][2 * m],  ik = Rtab[bsel][k][2 * m + 1];
            float rp = Rtab[bsel][k2][2 * m], ip = Rtab[bsel][k2][2 * m + 1];
            float sg = (pt == 0) ? 1.f : (((m >> (pt - 1)) & 1) ? -1.f : 1.f);
            float wr = sg * (rk * rp + ik * ip);     // R_k * conj(R_k2)
            float wi = sg * (ik * rp - rk * ip);
            if (m < 16) { Elo.x += wr; Elo.y += wi; }
            else        { Ehi.x += wr; Ehi.y += wi; }
        }
        sH[bsel][pt][2 * kk]     = Elo.x + Ehi.x;
        sH[bsel][pt][2 * kk + 1] = Elo.y + Ehi.y;
        if (pt == 0) {
            float ccss = c15 * c15 - s15 * s15;
            sD[bsel][2 * kk]     = Elo.x + ccss * Ehi.x;
            sD[bsel][2 * kk + 1] = Elo.y + ccss * Ehi.y;
            float cs = c15 * s15;
            sE[bsel][2 * kk]     = cs * Ehi.x;
            sE[bsel][2 * kk + 1] = cs * Ehi.y;
        }
    }
    __syncthreads();

    // ---- phase 2: 4 part-slices sequentially; tau = part*256 + tid ----
    int x0 = 2 * (tid & 31), x1 = x0 + 1;
    int x5 = (tid >> 4) & 1;

    f2 B0[2][2], B1[2][2];
    #pragma unroll
    for (int c = 0; c < 2; ++c)
        #pragma unroll
        for (int pq = 0; pq < 2; ++pq) {
            B0[c][pq] = Btab[c * 2 + pq][x0];
            B1[c][pq] = Btab[c * 2 + pq][x1];
        }

    float Pa = 0.f, P9 = 0.f, P10 = 0.f, Pd = 0.f;
    float S0 = 0.f, S1 = 0.f, S2 = 0.f, S3 = 0.f, S4 = 0.f;

    for (int part = 0; part < 4; ++part) {
        int bsel = part >> 1;
        int y = part * 8 + (tid >> 5);
        f2 Cv[2][2];
        #pragma unroll
        for (int pq = 0; pq < 2; ++pq)
            #pragma unroll
            for (int j = 0; j < 2; ++j)
                Cv[pq][j] = Ctab[(pq * 2 + j) * 2 + x5][y];

        f2 a[4], bb[4];
        #pragma unroll
        for (int c = 0; c < 2; ++c)
            #pragma unroll
            for (int j = 0; j < 2; ++j) {
                f2 s0 = cmul(B0[c][0], Cv[0][j]);
                f2 s1 = cmul(B0[c][1], Cv[1][j]);
                a[c * 2 + j] = f2{s0.x + s1.x, s0.y + s1.y};
                f2 t0 = cmul(B1[c][0], Cv[0][j]);
                f2 t1 = cmul(B1[c][1], Cv[1][j]);
                bb[c * 2 + j] = f2{t0.x + t1.x, t0.y + t1.y};
            }

        float sum_d[4], dif_d[4];
        #pragma unroll
        for (int k = 0; k < 4; ++k) {
            float pa = a[k].x * a[k].x + a[k].y * a[k].y;
            float pb = bb[k].x * bb[k].x + bb[k].y * bb[k].y;
            sum_d[k] = pa + pb;
            dif_d[k] = pa - pb;
        }
        f2 wS[6], wD[6];
        {
            int pi = 0;
            #pragma unroll
            for (int k = 0; k < 4; ++k)
                #pragma unroll
                for (int k2 = k + 1; k2 < 4; ++k2) {
                    f2 u = cmulc(a[k], a[k2]);
                    f2 v = cmulc(bb[k], bb[k2]);
                    wS[pi] = f2{u.x + v.x, u.y + v.y};
                    wD[pi] = f2{u.x - v.x, u.y - v.y};
                    ++pi;
                }
        }

        float F[6];
        #pragma unroll
        for (int pt = 0; pt < 6; ++pt) {
            const float* Hk = sH[bsel][pt];
            float f = 0.f;
            #pragma unroll
            for (int k = 0; k < 4; ++k) f += Hk[(k * 4 + k) * 2] * sum_d[k];
            int pi = 0;
            #pragma unroll
            for (int k = 0; k < 4; ++k)
                #pragma unroll
                for (int k2 = k + 1; k2 < 4; ++k2) {
                    float hr = Hk[(k * 4 + k2) * 2], hi = Hk[(k * 4 + k2) * 2 + 1];
                    f += 2.f * (hr * wS[pi].x - hi * wS[pi].y);
                    ++pi;
                }
            F[pt] = f;
        }
        float pd_i;
        {
            const float* Dk = sD[bsel];
            const float* Ek = sE[bsel];
            float f = 0.f;
            #pragma unroll
            for (int k = 0; k < 4; ++k) f += Dk[(k * 4 + k) * 2] * dif_d[k];
            int pi = 0;
            #pragma unroll
            for (int k = 0; k < 4; ++k)
                #pragma unroll
                for (int k2 = k + 1; k2 < 4; ++k2) {
                    float dr = Dk[(k * 4 + k2) * 2], di = Dk[(k * 4 + k2) * 2 + 1];
                    f += 2.f * (dr * wD[pi].x - di * wD[pi].y);
                    ++pi;
                }
            f2 z = f2{0.f, 0.f};
            #pragma unroll
            for (int k = 0; k < 4; ++k) {
                f2 v = f2{0.f, 0.f};
                #pragma unroll
                for (int k2 = 0; k2 < 4; ++k2) {
                    float er = Ek[(k * 4 + k2) * 2], ei = Ek[(k * 4 + k2) * 2 + 1];
                    v.x += er * bb[k2].x + ei * bb[k2].y;    // E * conj(b)
                    v.y += ei * bb[k2].x - er * bb[k2].y;
                }
                z.x += a[k].x * v.x - a[k].y * v.y;
                z.y += a[k].x * v.y + a[k].y * v.x;
            }
            pd_i = f - 4.f * z.y;
        }

        Pa  += F[0];
        P9  += (part & 1) ? -F[0] : F[0];
        P10 += (part & 2) ? -F[0] : F[0];
        Pd  += pd_i;
        S0 += F[1]; S1 += F[2]; S2 += F[3]; S3 += F[4]; S4 += F[5];
    }

    // ---- reductions: WHT for Pa (tau bits 0-5), plain butterflies for the rest ----
    #pragma unroll
    for (int o = 1; o < 64; o <<= 1) {
        float tP = __shfl_xor(Pa, o);
        Pa = (lane & o) ? (tP - Pa) : (Pa + tP);
        Pd  += __shfl_xor(Pd, o);
        P9  += __shfl_xor(P9, o);
        P10 += __shfl_xor(P10, o);
        S0  += __shfl_xor(S0, o);
        S1  += __shfl_xor(S1, o);
        S2  += __shfl_xor(S2, o);
        S3  += __shfl_xor(S3, o);
        S4  += __shfl_xor(S4, o);
    }
    if ((lane & (lane - 1)) == 0) {       // lanes 0,1,2,4,8,16,32
        int slot = (lane == 0) ? 0 : (31 - __clz((unsigned)lane)) + 1;  // 1..6
        redP[wv][slot] = Pa;
    }
    if (lane == 0) {
        redQ[wv][0] = Pd;  redQ[wv][1] = P9;  redQ[wv][2] = P10;
        redQ[wv][3] = S0;  redQ[wv][4] = S1;  redQ[wv][5] = S2;
        redQ[wv][6] = S3;  redQ[wv][7] = S4;
    }
    __syncthreads();
    if (tid < 16) {
        int q = tid;
        float v;
        if (q == 0)      v = redQ[0][0] + redQ[1][0] + redQ[2][0] + redQ[3][0];
        else if (q < 7)  v = redP[0][q] + redP[1][q] + redP[2][q] + redP[3][q];
        else if (q == 7) v = redP[0][0] - redP[1][0] + redP[2][0] - redP[3][0]; // tau b6
        else if (q == 8) v = redP[0][0] + redP[1][0] - redP[2][0] - redP[3][0]; // tau b7
        else if (q == 9)  v = redQ[0][1] + redQ[1][1] + redQ[2][1] + redQ[3][1];
        else if (q == 10) v = redQ[0][2] + redQ[1][2] + redQ[2][2] + redQ[3][2];
        else              v = redQ[0][q-8] + redQ[1][q-8] + redQ[2][q-8] + redQ[3][q-8];
        evf[q] = v;
    }
    __syncthreads();

    // ---- head: logits + log_softmax ----
    if (tid < 16) {
        int c = tid;
        float v = fcb[c];
        #pragma unroll
        for (int q = 0; q < 16; ++q) v += evf[q] * fcw[c * 16 + q];
        lgf[c] = v;
    }
    __syncthreads();
    if (tid < 16) {
        float mx = -1e30f;
        #pragma unroll
        for (int c2 = 0; c2 < 16; ++c2) mx = fmaxf(mx, lgf[c2]);
        float se = 0.f;
        #pragma unroll
        for (int c2 = 0; c2 < 16; ++c2) se += expf(lgf[c2] - mx);
        out[b * 16 + tid] = lgf[tid] - (mx + logf(se));
    }
}

// ---------------- launch ----------------
extern "C" void kernel_launch(void* const* d_in, const int* in_sizes, int n_in,
                              void* d_out, int out_size, void* d_ws, size_t ws_size,
                              hipStream_t stream) {
    const float* x    = (const float*)d_in[0];
    const float* cw   = (const float*)d_in[1];
    const float* cb   = (const float*)d_in[2];
    const float* rot1 = (const float*)d_in[3];
    const float* crx1 = (const float*)d_in[4];
    const float* rot2 = (const float*)d_in[5];
    const float* crx2 = (const float*)d_in[6];
    const float* fcw  = (const float*)d_in[7];
    const float* fcb  = (const float*)d_in[8];

    float* p = (float*)d_ws;   // 4096 floats

    pool_kernel<<<4096, 256, 0, stream>>>(x, p);
    qfin<<<128, 256, 0, stream>>>(p, cw, cb, rot1, crx1, rot2, crx2,
                                  fcw, fcb, (float*)d_out);
}

// Round 16
// 27.843 us; speedup vs baseline: 4.5516x; 1.1101x over previous
//
#include <hip/hip_runtime.h>
#include <hip/hip_bf16.h>

typedef float f2 __attribute__((ext_vector_type(2)));

// ---------------- shuffle-gate: merged 2x2 gate, amp-per-lane ----------------
// u: 16 floats {U | M1}; kt = target lane-bit; kc = control lane-bit (<0: plain)
__device__ __forceinline__ f2 sgate(f2 a, int lane, int kt, int kc, const float* u) {
    f2 p;
    p.x = __shfl_xor(a.x, 1 << kt);
    p.y = __shfl_xor(a.y, 1 << kt);
    const float* uu = u + ((kc >= 0 && ((lane >> kc) & 1)) ? 8 : 0);
    int bit = (lane >> kt) & 1;
    float cAr = bit ? uu[6] : uu[0], cAi = bit ? uu[7] : uu[1];
    float cPr = bit ? uu[4] : uu[2], cPi = bit ? uu[5] : uu[3];
    f2 r;
    r.x = cAr * a.x - cAi * a.y + cPr * p.x - cPi * p.y;
    r.y = cAr * a.y + cAi * a.x + cPr * p.y + cPi * p.x;
    return r;
}

__device__ __forceinline__ f2 cmul(f2 A, f2 B) {
    return f2{A.x * B.x - A.y * B.y, A.x * B.y + A.y * B.x};
}
// x * conj(y)
__device__ __forceinline__ f2 cmulc(f2 x, f2 y) {
    return f2{x.x * y.x + x.y * y.y, x.y * y.x - x.x * y.y};
}

// ---------------- single kernel: pool + prep + quadratic forms + EV + head ----------
// grid = 128 (one block per batch), 256 threads. All tables LDS-resident.
__global__ __launch_bounds__(256) void qall2(const float* __restrict__ x,
                                             const float* __restrict__ cw,
                                             const float* __restrict__ cb,
                                             const float* __restrict__ rot1,
                                             const float* __restrict__ crx1,
                                             const float* __restrict__ rot2,
                                             const float* __restrict__ crx2,
                                             const float* __restrict__ fcw,
                                             const float* __restrict__ fcb,
                                             float* __restrict__ out) {
    __shared__ float pp[32];
    __shared__ float uM[32][16];     // [l*16+q] merged {U | RX(crx[q-1])U}
    __shared__ float cs15[4];        // [l0 c,s | l1 c,s] for CRX(15,0)
    __shared__ f2 ell[64];
    __shared__ f2 Rr[2][64];
    __shared__ f2 Wl[2][32];
    __shared__ f2 Btab[4][64];       // [c*2+p][x]
    __shared__ f2 Ctab[8][32];       // [(p*2+j)*2+p2][y]
    __shared__ float Rtab[2][4][64]; // [bsel][c*2+j][2m+ri]
    __shared__ float sH[2][6][32];   // Gram mats (pt: P, m-bit0..4), f2-flattened
    __shared__ float sD[2][32];
    __shared__ float sE[2][32];
    __shared__ float redP[4][7];
    __shared__ float redQ[4][8];     // Pd, P9, P10, S0..S4
    __shared__ float evf[16];
    __shared__ float lgf[16];
    int tid = threadIdx.x;
    int b = blockIdx.x;

    // ---- phase 0: adaptive pool of this batch's x (512 KB, LLC-hot) ----
    // group g = tid>>3 handles pooled cell g = c*16 + dd*4 + hh; sub = tid&7
    {
        int g = tid >> 3, sub = tid & 7;
        int c = g >> 4, dd = (g >> 2) & 3, hh = g & 3;
        const float4* xb = (const float4*)(x + (size_t)b * 131072)
                         + c * 16384 + dd * 4096 + hh * 256;
        float sum = 0.f;
        #pragma unroll
        for (int d = 0; d < 4; ++d) {
            const float4* ch = xb + d * 1024;
            #pragma unroll 8
            for (int i = 0; i < 32; ++i) {
                float4 v = ch[i * 8 + sub];
                sum += v.x + v.y + v.z + v.w;
            }
        }
        sum += __shfl_xor(sum, 1);
        sum += __shfl_xor(sum, 2);
        sum += __shfl_xor(sum, 4);
        if (sub == 0) pp[g] = sum * (1.0f / 4096.0f);
    }
    __syncthreads();

    // ---- merged gate matrices: 32 threads, one per (q, l) ----
    if (tid < 32) {
        int q = tid & 15, l = tid >> 4;
        float f = cb[q];
        #pragma unroll
        for (int jj = 0; jj < 32; ++jj) f += pp[jj] * cw[q * 32 + jj];
        float cr = cosf(0.5f * f), sr = sinf(0.5f * f);
        const float* rw = (l == 0 ? rot1 : rot2) + q * 3;
        float phi = rw[0], th = rw[1], om = rw[2];
        float ct = cosf(0.5f * th), st = sinf(0.5f * th);
        float aa = 0.5f * (phi + om), dd = 0.5f * (phi - om);
        float ca = cosf(aa), sa = sinf(aa), cd = cosf(dd), sd = sinf(dd);
        float R00r =  ct * ca, R00i = -ct * sa;
        float R01r = -st * cd, R01i = -st * sd;
        float R10r =  st * cd, R10i = -st * sd;
        float R11r =  ct * ca, R11i =  ct * sa;
        float u0 = cr * R00r + sr * R01i;
        float u1 = cr * R00i - sr * R01r;
        float u2 = cr * R01r + sr * R00i;
        float u3 = cr * R01i - sr * R00r;
        float u4 = cr * R10r + sr * R11i;
        float u5 = cr * R10i - sr * R11r;
        float u6 = cr * R11r + sr * R10i;
        float u7 = cr * R11i - sr * R10r;
        float g[16];
        g[0] = u0; g[1] = u1; g[2] = u2; g[3] = u3;
        g[4] = u4; g[5] = u5; g[6] = u6; g[7] = u7;
        if (q >= 1) {
            float thc = (l == 0 ? crx1 : crx2)[q - 1];
            float c2 = cosf(0.5f * thc), s2 = sinf(0.5f * thc);
            g[8]  = c2*u0 + s2*u5;  g[9]  = c2*u1 - s2*u4;
            g[10] = c2*u2 + s2*u7;  g[11] = c2*u3 - s2*u6;
            g[12] = c2*u4 + s2*u1;  g[13] = c2*u5 - s2*u0;
            g[14] = c2*u6 + s2*u3;  g[15] = c2*u7 - s2*u2;
        } else {
            #pragma unroll
            for (int k = 0; k < 8; ++k) g[8 + k] = g[k];
        }
        float* s = uM[l * 16 + q];
        #pragma unroll
        for (int k = 0; k < 16; ++k) s[k] = g[k];
        if (q == 15) {
            float th2 = (l == 0 ? crx1 : crx2)[15];
            cs15[l * 2]     = cosf(0.5f * th2);
            cs15[l * 2 + 1] = sinf(0.5f * th2);
        }
    }
    __syncthreads();

    int wv = tid >> 6, lane = tid & 63;

    // ---- stage A: ell (wave 0), Rr_p (waves 1,2), W_j (wave 3 halves) ----
    if (wv == 0) {
        f2 a = (lane == 0) ? f2{1.f, 0.f} : f2{0.f, 0.f};
        a = sgate(a, lane, 0, -1, uM[0]);                 // L0 G0
        #pragma unroll
        for (int q = 1; q <= 5; ++q) a = sgate(a, lane, q, q - 1, uM[q]);
        ell[lane] = a;
    } else if (wv <= 2) {
        int pidx = wv - 1;
        const float* m6 = uM[6] + pidx * 8;               // M_p = L0-G6 variant
        f2 a = f2{0.f, 0.f};
        if (lane == 0) a = f2{m6[0], m6[1]};
        if (lane == 1) a = f2{m6[4], m6[5]};
        #pragma unroll
        for (int q = 7; q <= 11; ++q) a = sgate(a, lane, q - 6, q - 7, uM[q]);
        Rr[pidx][lane] = a;
    } else {
        int j = lane >> 5, lm = lane & 31;
        f2 a = (lm == j) ? f2{1.f, 0.f} : f2{0.f, 0.f};   // e_j at bit11 (m bit 0)
        #pragma unroll
        for (int q = 12; q <= 15; ++q) a = sgate(a, lane, q - 11, q - 12, uM[q]);
        Wl[j][lm] = a;
    }
    __syncthreads();

    // ---- stage B: B (4x64), C (8x32), R (8x32) — each wave does one of each ----
    {   // B_{c,p}: c = wv>>1, p = wv&1
        int c = wv >> 1, pb = wv & 1;
        f2 a = ell[lane];
        if (((lane >> 5) & 1) != pb) a = f2{0.f, 0.f};    // P_p on bit 5
        if (c) {                                          // RX0(L0 crx15) on bit 0
            f2 pr; pr.x = __shfl_xor(a.x, 1); pr.y = __shfl_xor(a.y, 1);
            f2 n = cs15[0] * a;
            n.x += cs15[1] * pr.y; n.y -= cs15[1] * pr.x;
            a = n;
        }
        a = sgate(a, lane, 0, -1, uM[16]);                // L1 G0
        #pragma unroll
        for (int q = 1; q <= 5; ++q) a = sgate(a, lane, q, q - 1, uM[16 + q]);
        Btab[wv][lane] = a;
    }
    {   // C_{p,j,p2}: p = wv>>1, p2 = wv&1, halves j
        int pidx = wv >> 1, p2 = wv & 1, j = lane >> 5, lm = lane & 31;
        f2 a = Rr[pidx][(j << 5) | lm];                   // restrict bit11 = j
        a = sgate(a, lane, 0, -1, uM[16 + 6] + p2 * 8);   // M_{p2} = L1-G6 variant
        #pragma unroll
        for (int q = 7; q <= 10; ++q) a = sgate(a, lane, q - 6, q - 7, uM[16 + q]);
        Ctab[(pidx * 2 + j) * 2 + p2][lm] = a;
    }
    {   // R_{c,j}^{bsel}: c = wv>>1, bsel = wv&1, halves j
        int c = wv >> 1, bsel = wv & 1, j = lane >> 5, lm = lane & 31;
        f2 a = Wl[j][lm];
        if (((lm >> 4) & 1) != c) a = f2{0.f, 0.f};       // mask bit15 = c
        a = sgate(a, lane, 0, -1, uM[16 + 11] + bsel * 8);  // L1 G11^{bsel}
        #pragma unroll
        for (int q = 12; q <= 15; ++q) a = sgate(a, lane, q - 11, q - 12, uM[16 + q]);
        Rtab[bsel][c * 2 + j][2 * lm]     = a.x;
        Rtab[bsel][c * 2 + j][2 * lm + 1] = a.y;
    }
    __syncthreads();

    // ---- Gram matrices: 192 threads, one per (bsel, pattern, k, k2) -> LDS ----
    if (tid < 192) {
        int bsel = tid / 96, rem = tid % 96, pt = rem >> 4, kk = rem & 15;
        int k = kk >> 2, k2 = kk & 3;
        float c15 = cs15[2], s15 = cs15[3];
        f2 Elo = f2{0.f, 0.f}, Ehi = f2{0.f, 0.f};
        #pragma unroll
        for (int m = 0; m < 32; ++m) {
            float rk = Rtab[bsel][k][2 * m],  ik = Rtab[bsel][k][2 * m + 1];
            float rp = Rtab[bsel][k2][2 * m], ip = Rtab[bsel][k2][2 * m + 1];
            float sg = (pt == 0) ? 1.f : (((m >> (pt - 1)) & 1) ? -1.f : 1.f);
            float wr = sg * (rk * rp + ik * ip);     // R_k * conj(R_k2)
            float wi = sg * (ik * rp - rk * ip);
            if (m < 16) { Elo.x += wr; Elo.y += wi; }
            else        { Ehi.x += wr; Ehi.y += wi; }
        }
        sH[bsel][pt][2 * kk]     = Elo.x + Ehi.x;
        sH[bsel][pt][2 * kk + 1] = Elo.y + Ehi.y;
        if (pt == 0) {
            float ccss = c15 * c15 - s15 * s15;
            sD[bsel][2 * kk]     = Elo.x + ccss * Ehi.x;
            sD[bsel][2 * kk + 1] = Elo.y + ccss * Ehi.y;
            float cs = c15 * s15;
            sE[bsel][2 * kk]     = cs * Ehi.x;
            sE[bsel][2 * kk + 1] = cs * Ehi.y;
        }
    }
    __syncthreads();

    // ---- phase 2: 4 part-slices sequentially; tau = part*256 + tid ----
    int x0 = 2 * (tid & 31), x1 = x0 + 1;
    int x5 = (tid >> 4) & 1;

    f2 B0[2][2], B1[2][2];
    #pragma unroll
    for (int c = 0; c < 2; ++c)
        #pragma unroll
        for (int pq = 0; pq < 2; ++pq) {
            B0[c][pq] = Btab[c * 2 + pq][x0];
            B1[c][pq] = Btab[c * 2 + pq][x1];
        }

    float Pa = 0.f, P9 = 0.f, P10 = 0.f, Pd = 0.f;
    float S0 = 0.f, S1 = 0.f, S2 = 0.f, S3 = 0.f, S4 = 0.f;

    for (int part = 0; part < 4; ++part) {
        int bsel = part >> 1;
        int y = part * 8 + (tid >> 5);
        f2 Cv[2][2];
        #pragma unroll
        for (int pq = 0; pq < 2; ++pq)
            #pragma unroll
            for (int j = 0; j < 2; ++j)
                Cv[pq][j] = Ctab[(pq * 2 + j) * 2 + x5][y];

        f2 a[4], bb[4];
        #pragma unroll
        for (int c = 0; c < 2; ++c)
            #pragma unroll
            for (int j = 0; j < 2; ++j) {
                f2 s0 = cmul(B0[c][0], Cv[0][j]);
                f2 s1 = cmul(B0[c][1], Cv[1][j]);
                a[c * 2 + j] = f2{s0.x + s1.x, s0.y + s1.y};
                f2 t0 = cmul(B1[c][0], Cv[0][j]);
                f2 t1 = cmul(B1[c][1], Cv[1][j]);
                bb[c * 2 + j] = f2{t0.x + t1.x, t0.y + t1.y};
            }

        float sum_d[4], dif_d[4];
        #pragma unroll
        for (int k = 0; k < 4; ++k) {
            float pa = a[k].x * a[k].x + a[k].y * a[k].y;
            float pb = bb[k].x * bb[k].x + bb[k].y * bb[k].y;
            sum_d[k] = pa + pb;
            dif_d[k] = pa - pb;
        }
        f2 wS[6], wD[6];
        {
            int pi = 0;
            #pragma unroll
            for (int k = 0; k < 4; ++k)
                #pragma unroll
                for (int k2 = k + 1; k2 < 4; ++k2) {
                    f2 u = cmulc(a[k], a[k2]);
                    f2 v = cmulc(bb[k], bb[k2]);
                    wS[pi] = f2{u.x + v.x, u.y + v.y};
                    wD[pi] = f2{u.x - v.x, u.y - v.y};
                    ++pi;
                }
        }

        float F[6];
        #pragma unroll
        for (int pt = 0; pt < 6; ++pt) {
            const float* Hk = sH[bsel][pt];
            float f = 0.f;
            #pragma unroll
            for (int k = 0; k < 4; ++k) f += Hk[(k * 4 + k) * 2] * sum_d[k];
            int pi = 0;
            #pragma unroll
            for (int k = 0; k < 4; ++k)
                #pragma unroll
                for (int k2 = k + 1; k2 < 4; ++k2) {
                    float hr = Hk[(k * 4 + k2) * 2], hi = Hk[(k * 4 + k2) * 2 + 1];
                    f += 2.f * (hr * wS[pi].x - hi * wS[pi].y);
                    ++pi;
                }
            F[pt] = f;
        }
        float pd_i;
        {
            const float* Dk = sD[bsel];
            const float* Ek = sE[bsel];
            float f = 0.f;
            #pragma unroll
            for (int k = 0; k < 4; ++k) f += Dk[(k * 4 + k) * 2] * dif_d[k];
            int pi = 0;
            #pragma unroll
            for (int k = 0; k < 4; ++k)
                #pragma unroll
                for (int k2 = k + 1; k2 < 4; ++k2) {
                    float dr = Dk[(k * 4 + k2) * 2], di = Dk[(k * 4 + k2) * 2 + 1];
                    f += 2.f * (dr * wD[pi].x - di * wD[pi].y);
                    ++pi;
                }
            f2 z = f2{0.f, 0.f};
            #pragma unroll
            for (int k = 0; k < 4; ++k) {
                f2 v = f2{0.f, 0.f};
                #pragma unroll
                for (int k2 = 0; k2 < 4; ++k2) {
                    float er = Ek[(k * 4 + k2) * 2], ei = Ek[(k * 4 + k2) * 2 + 1];
                    v.x += er * bb[k2].x + ei * bb[k2].y;    // E * conj(b)
                    v.y += ei * bb[k2].x - er * bb[k2].y;
                }
                z.x += a[k].x * v.x - a[k].y * v.y;
                z.y += a[k].x * v.y + a[k].y * v.x;
            }
            pd_i = f - 4.f * z.y;
        }

        Pa  += F[0];
        P9  += (part & 1) ? -F[0] : F[0];
        P10 += (part & 2) ? -F[0] : F[0];
        Pd  += pd_i;
        S0 += F[1]; S1 += F[2]; S2 += F[3]; S3 += F[4]; S4 += F[5];
    }

    // ---- reductions: WHT for Pa (tau bits 0-5), plain butterflies for the rest ----
    #pragma unroll
    for (int o = 1; o < 64; o <<= 1) {
        float tP = __shfl_xor(Pa, o);
        Pa = (lane & o) ? (tP - Pa) : (Pa + tP);
        Pd  += __shfl_xor(Pd, o);
        P9  += __shfl_xor(P9, o);
        P10 += __shfl_xor(P10, o);
        S0  += __shfl_xor(S0, o);
        S1  += __shfl_xor(S1, o);
        S2  += __shfl_xor(S2, o);
        S3  += __shfl_xor(S3, o);
        S4  += __shfl_xor(S4, o);
    }
    if ((lane & (lane - 1)) == 0) {       // lanes 0,1,2,4,8,16,32
        int slot = (lane == 0) ? 0 : (31 - __clz((unsigned)lane)) + 1;  // 1..6
        redP[wv][slot] = Pa;
    }
    if (lane == 0) {
        redQ[wv][0] = Pd;  redQ[wv][1] = P9;  redQ[wv][2] = P10;
        redQ[wv][3] = S0;  redQ[wv][4] = S1;  redQ[wv][5] = S2;
        redQ[wv][6] = S3;  redQ[wv][7] = S4;
    }
    __syncthreads();
    if (tid < 16) {
        int q = tid;
        float v;
        if (q == 0)      v = redQ[0][0] + redQ[1][0] + redQ[2][0] + redQ[3][0];
        else if (q < 7)  v = redP[0][q] + redP[1][q] + redP[2][q] + redP[3][q];
        else if (q == 7) v = redP[0][0] - redP[1][0] + redP[2][0] - redP[3][0]; // tau b6
        else if (q == 8) v = redP[0][0] + redP[1][0] - redP[2][0] - redP[3][0]; // tau b7
        else if (q == 9)  v = redQ[0][1] + redQ[1][1] + redQ[2][1] + redQ[3][1];
        else if (q == 10) v = redQ[0][2] + redQ[1][2] + redQ[2][2] + redQ[3][2];
        else              v = redQ[0][q-8] + redQ[1][q-8] + redQ[2][q-8] + redQ[3][q-8];
        evf[q] = v;
    }
    __syncthreads();

    // ---- head: logits + log_softmax ----
    if (tid < 16) {
        int c = tid;
        float v = fcb[c];
        #pragma unroll
        for (int q = 0; q < 16; ++q) v += evf[q] * fcw[c * 16 + q];
        lgf[c] = v;
    }
    __syncthreads();
    if (tid < 16) {
        float mx = -1e30f;
        #pragma unroll
        for (int c2 = 0; c2 < 16; ++c2) mx = fmaxf(mx, lgf[c2]);
        float se = 0.f;
        #pragma unroll
        for (int c2 = 0; c2 < 16; ++c2) se += expf(lgf[c2] - mx);
        out[b * 16 + tid] = lgf[tid] - (mx + logf(se));
    }
}

// ---------------- launch ----------------
extern "C" void kernel_launch(void* const* d_in, const int* in_sizes, int n_in,
                              void* d_out, int out_size, void* d_ws, size_t ws_size,
                              hipStream_t stream) {
    const float* x    = (const float*)d_in[0];
    const float* cw   = (const float*)d_in[1];
    const float* cb   = (const float*)d_in[2];
    const float* rot1 = (const float*)d_in[3];
    const float* crx1 = (const float*)d_in[4];
    const float* rot2 = (const float*)d_in[5];
    const float* crx2 = (const float*)d_in[6];
    const float* fcw  = (const float*)d_in[7];
    const float* fcb  = (const float*)d_in[8];

    qall2<<<128, 256, 0, stream>>>(x, cw, cb, rot1, crx1, rot2, crx2,
                                   fcw, fcb, (float*)d_out);
}

// Round 17
// 27.343 us; speedup vs baseline: 4.6348x; 1.0183x over previous
//
#include <hip/hip_runtime.h>
#include <hip/hip_bf16.h>

typedef float f2 __attribute__((ext_vector_type(2)));

// ---------------- shuffle-gate: merged 2x2 gate, amp-per-lane ----------------
// u: 16 floats {U | M1}; kt = target lane-bit; kc = control lane-bit (<0: plain)
__device__ __forceinline__ f2 sgate(f2 a, int lane, int kt, int kc, const float* u) {
    f2 p;
    p.x = __shfl_xor(a.x, 1 << kt);
    p.y = __shfl_xor(a.y, 1 << kt);
    const float* uu = u + ((kc >= 0 && ((lane >> kc) & 1)) ? 8 : 0);
    int bit = (lane >> kt) & 1;
    float cAr = bit ? uu[6] : uu[0], cAi = bit ? uu[7] : uu[1];
    float cPr = bit ? uu[4] : uu[2], cPi = bit ? uu[5] : uu[3];
    f2 r;
    r.x = cAr * a.x - cAi * a.y + cPr * p.x - cPi * p.y;
    r.y = cAr * a.y + cAi * a.x + cPr * p.y + cPi * p.x;
    return r;
}

__device__ __forceinline__ f2 cmul(f2 A, f2 B) {
    return f2{A.x * B.x - A.y * B.y, A.x * B.y + A.y * B.x};
}
// x * conj(y)
__device__ __forceinline__ f2 cmulc(f2 x, f2 y) {
    return f2{x.x * y.x + x.y * y.y, x.y * y.x - x.x * y.y};
}

// ---------------- single kernel: pool + prep + quadratic forms + EV + head ----------
// grid = 128 (one block per batch), 512 threads. All tables LDS-resident.
// Waves 0-3: preamble (proven R15 code). Waves 4-7: idle through preamble.
// Phase 2: wave-group g = wv>>2 handles parts {2g, 2g+1}.
__global__ __launch_bounds__(512) void qall2(const float* __restrict__ x,
                                             const float* __restrict__ cw,
                                             const float* __restrict__ cb,
                                             const float* __restrict__ rot1,
                                             const float* __restrict__ crx1,
                                             const float* __restrict__ rot2,
                                             const float* __restrict__ crx2,
                                             const float* __restrict__ fcw,
                                             const float* __restrict__ fcb,
                                             float* __restrict__ out) {
    __shared__ float pp[32];
    __shared__ float uM[32][16];     // [l*16+q] merged {U | RX(crx[q-1])U}
    __shared__ float cs15[4];        // [l0 c,s | l1 c,s] for CRX(15,0)
    __shared__ f2 ell[64];
    __shared__ f2 Rr[2][64];
    __shared__ f2 Wl[2][32];
    __shared__ f2 Btab[4][64];       // [c*2+p][x]
    __shared__ f2 Ctab[8][32];       // [(p*2+j)*2+p2][y]
    __shared__ float Rtab[2][4][64]; // [bsel][c*2+j][2m+ri]
    __shared__ float sH[2][6][32];   // Gram mats (pt: P, m-bit0..4), f2-flattened
    __shared__ float sD[2][32];
    __shared__ float sE[2][32];
    __shared__ float redP[8][7];
    __shared__ float redQ[8][7];     // Pd, P9, S0..S4
    __shared__ float evf[16];
    __shared__ float lgf[16];
    int tid = threadIdx.x;
    int b = blockIdx.x;

    // ---- phase 0: adaptive pool of this batch's x (512 KB, LLC-hot) ----
    // group g = tid>>4 handles pooled cell; sub = tid&15 ; 64 float4/thread
    {
        int g = tid >> 4, sub = tid & 15;
        int c = g >> 4, dd = (g >> 2) & 3, hh = g & 3;
        const float4* xb = (const float4*)(x + (size_t)b * 131072)
                         + c * 16384 + dd * 4096 + hh * 256;
        float sum = 0.f;
        #pragma unroll
        for (int d = 0; d < 4; ++d) {
            const float4* ch = xb + d * 1024;
            #pragma unroll 8
            for (int i = 0; i < 16; ++i) {
                float4 v = ch[i * 16 + sub];
                sum += v.x + v.y + v.z + v.w;
            }
        }
        sum += __shfl_xor(sum, 1);
        sum += __shfl_xor(sum, 2);
        sum += __shfl_xor(sum, 4);
        sum += __shfl_xor(sum, 8);
        if (sub == 0) pp[g] = sum * (1.0f / 4096.0f);
    }
    __syncthreads();

    // ---- merged gate matrices: 32 threads, one per (q, l) ----
    if (tid < 32) {
        int q = tid & 15, l = tid >> 4;
        float f = cb[q];
        #pragma unroll
        for (int jj = 0; jj < 32; ++jj) f += pp[jj] * cw[q * 32 + jj];
        float cr = cosf(0.5f * f), sr = sinf(0.5f * f);
        const float* rw = (l == 0 ? rot1 : rot2) + q * 3;
        float phi = rw[0], th = rw[1], om = rw[2];
        float ct = cosf(0.5f * th), st = sinf(0.5f * th);
        float aa = 0.5f * (phi + om), dd = 0.5f * (phi - om);
        float ca = cosf(aa), sa = sinf(aa), cd = cosf(dd), sd = sinf(dd);
        float R00r =  ct * ca, R00i = -ct * sa;
        float R01r = -st * cd, R01i = -st * sd;
        float R10r =  st * cd, R10i = -st * sd;
        float R11r =  ct * ca, R11i =  ct * sa;
        float u0 = cr * R00r + sr * R01i;
        float u1 = cr * R00i - sr * R01r;
        float u2 = cr * R01r + sr * R00i;
        float u3 = cr * R01i - sr * R00r;
        float u4 = cr * R10r + sr * R11i;
        float u5 = cr * R10i - sr * R11r;
        float u6 = cr * R11r + sr * R10i;
        float u7 = cr * R11i - sr * R10r;
        float g[16];
        g[0] = u0; g[1] = u1; g[2] = u2; g[3] = u3;
        g[4] = u4; g[5] = u5; g[6] = u6; g[7] = u7;
        if (q >= 1) {
            float thc = (l == 0 ? crx1 : crx2)[q - 1];
            float c2 = cosf(0.5f * thc), s2 = sinf(0.5f * thc);
            g[8]  = c2*u0 + s2*u5;  g[9]  = c2*u1 - s2*u4;
            g[10] = c2*u2 + s2*u7;  g[11] = c2*u3 - s2*u6;
            g[12] = c2*u4 + s2*u1;  g[13] = c2*u5 - s2*u0;
            g[14] = c2*u6 + s2*u3;  g[15] = c2*u7 - s2*u2;
        } else {
            #pragma unroll
            for (int k = 0; k < 8; ++k) g[8 + k] = g[k];
        }
        float* s = uM[l * 16 + q];
        #pragma unroll
        for (int k = 0; k < 16; ++k) s[k] = g[k];
        if (q == 15) {
            float th2 = (l == 0 ? crx1 : crx2)[15];
            cs15[l * 2]     = cosf(0.5f * th2);
            cs15[l * 2 + 1] = sinf(0.5f * th2);
        }
    }
    __syncthreads();

    int wv = tid >> 6, lane = tid & 63;

    // ---- stage A (waves 0-3 only) ----
    if (wv == 0) {
        f2 a = (lane == 0) ? f2{1.f, 0.f} : f2{0.f, 0.f};
        a = sgate(a, lane, 0, -1, uM[0]);                 // L0 G0
        #pragma unroll
        for (int q = 1; q <= 5; ++q) a = sgate(a, lane, q, q - 1, uM[q]);
        ell[lane] = a;
    } else if (wv <= 2) {
        int pidx = wv - 1;
        const float* m6 = uM[6] + pidx * 8;               // M_p = L0-G6 variant
        f2 a = f2{0.f, 0.f};
        if (lane == 0) a = f2{m6[0], m6[1]};
        if (lane == 1) a = f2{m6[4], m6[5]};
        #pragma unroll
        for (int q = 7; q <= 11; ++q) a = sgate(a, lane, q - 6, q - 7, uM[q]);
        Rr[pidx][lane] = a;
    } else if (wv == 3) {
        int j = lane >> 5, lm = lane & 31;
        f2 a = (lm == j) ? f2{1.f, 0.f} : f2{0.f, 0.f};   // e_j at bit11 (m bit 0)
        #pragma unroll
        for (int q = 12; q <= 15; ++q) a = sgate(a, lane, q - 11, q - 12, uM[q]);
        Wl[j][lm] = a;
    }
    __syncthreads();

    // ---- stage B (waves 0-3 only) ----
    if (wv < 4) {
        {   // B_{c,p}: c = wv>>1, p = wv&1
            int c = wv >> 1, pb = wv & 1;
            f2 a = ell[lane];
            if (((lane >> 5) & 1) != pb) a = f2{0.f, 0.f};    // P_p on bit 5
            if (c) {                                          // RX0(L0 crx15) on bit 0
                f2 pr; pr.x = __shfl_xor(a.x, 1); pr.y = __shfl_xor(a.y, 1);
                f2 n = cs15[0] * a;
                n.x += cs15[1] * pr.y; n.y -= cs15[1] * pr.x;
                a = n;
            }
            a = sgate(a, lane, 0, -1, uM[16]);                // L1 G0
            #pragma unroll
            for (int q = 1; q <= 5; ++q) a = sgate(a, lane, q, q - 1, uM[16 + q]);
            Btab[wv][lane] = a;
        }
        {   // C_{p,j,p2}: p = wv>>1, p2 = wv&1, halves j
            int pidx = wv >> 1, p2 = wv & 1, j = lane >> 5, lm = lane & 31;
            f2 a = Rr[pidx][(j << 5) | lm];                   // restrict bit11 = j
            a = sgate(a, lane, 0, -1, uM[16 + 6] + p2 * 8);   // M_{p2} = L1-G6 variant
            #pragma unroll
            for (int q = 7; q <= 10; ++q) a = sgate(a, lane, q - 6, q - 7, uM[16 + q]);
            Ctab[(pidx * 2 + j) * 2 + p2][lm] = a;
        }
        {   // R_{c,j}^{bsel}: c = wv>>1, bsel = wv&1, halves j
            int c = wv >> 1, bsel = wv & 1, j = lane >> 5, lm = lane & 31;
            f2 a = Wl[j][lm];
            if (((lm >> 4) & 1) != c) a = f2{0.f, 0.f};       // mask bit15 = c
            a = sgate(a, lane, 0, -1, uM[16 + 11] + bsel * 8);  // L1 G11^{bsel}
            #pragma unroll
            for (int q = 12; q <= 15; ++q) a = sgate(a, lane, q - 11, q - 12, uM[16 + q]);
            Rtab[bsel][c * 2 + j][2 * lm]     = a.x;
            Rtab[bsel][c * 2 + j][2 * lm + 1] = a.y;
        }
    }
    __syncthreads();

    // ---- Gram matrices: 192 threads, one per (bsel, pattern, k, k2) -> LDS ----
    if (tid < 192) {
        int bsel = tid / 96, rem = tid % 96, pt = rem >> 4, kk = rem & 15;
        int k = kk >> 2, k2 = kk & 3;
        float c15 = cs15[2], s15 = cs15[3];
        f2 Elo = f2{0.f, 0.f}, Ehi = f2{0.f, 0.f};
        #pragma unroll
        for (int m = 0; m < 32; ++m) {
            float rk = Rtab[bsel][k][2 * m],  ik = Rtab[bsel][k][2 * m + 1];
            float rp = Rtab[bsel][k2][2 * m], ip = Rtab[bsel][k2][2 * m + 1];
            float sg = (pt == 0) ? 1.f : (((m >> (pt - 1)) & 1) ? -1.f : 1.f);
            float wr = sg * (rk * rp + ik * ip);     // R_k * conj(R_k2)
            float wi = sg * (ik * rp - rk * ip);
            if (m < 16) { Elo.x += wr; Elo.y += wi; }
            else        { Ehi.x += wr; Ehi.y += wi; }
        }
        sH[bsel][pt][2 * kk]     = Elo.x + Ehi.x;
        sH[bsel][pt][2 * kk + 1] = Elo.y + Ehi.y;
        if (pt == 0) {
            float ccss = c15 * c15 - s15 * s15;
            sD[bsel][2 * kk]     = Elo.x + ccss * Ehi.x;
            sD[bsel][2 * kk + 1] = Elo.y + ccss * Ehi.y;
            float cs = c15 * s15;
            sE[bsel][2 * kk]     = cs * Ehi.x;
            sE[bsel][2 * kk + 1] = cs * Ehi.y;
        }
    }
    __syncthreads();

    // ---- phase 2: wave-group g handles parts {2g, 2g+1}; tau = part*256 + sub ----
    int sub = tid & 255;
    int grp = tid >> 8;                 // tau bit 9 = bsel
    int x0 = 2 * (sub & 31), x1 = x0 + 1;
    int x5 = (sub >> 4) & 1;

    f2 B0[2][2], B1[2][2];
    #pragma unroll
    for (int c = 0; c < 2; ++c)
        #pragma unroll
        for (int pq = 0; pq < 2; ++pq) {
            B0[c][pq] = Btab[c * 2 + pq][x0];
            B1[c][pq] = Btab[c * 2 + pq][x1];
        }

    float Pa = 0.f, P9 = 0.f, Pd = 0.f;
    float S0 = 0.f, S1 = 0.f, S2 = 0.f, S3 = 0.f, S4 = 0.f;

    #pragma unroll
    for (int pl = 0; pl < 2; ++pl) {
        int part = grp * 2 + pl;
        int bsel = grp;
        int y = part * 8 + (sub >> 5);
        f2 Cv[2][2];
        #pragma unroll
        for (int pq = 0; pq < 2; ++pq)
            #pragma unroll
            for (int j = 0; j < 2; ++j)
                Cv[pq][j] = Ctab[(pq * 2 + j) * 2 + x5][y];

        f2 a[4], bb[4];
        #pragma unroll
        for (int c = 0; c < 2; ++c)
            #pragma unroll
            for (int j = 0; j < 2; ++j) {
                f2 s0 = cmul(B0[c][0], Cv[0][j]);
                f2 s1 = cmul(B0[c][1], Cv[1][j]);
                a[c * 2 + j] = f2{s0.x + s1.x, s0.y + s1.y};
                f2 t0 = cmul(B1[c][0], Cv[0][j]);
                f2 t1 = cmul(B1[c][1], Cv[1][j]);
                bb[c * 2 + j] = f2{t0.x + t1.x, t0.y + t1.y};
            }

        float sum_d[4], dif_d[4];
        #pragma unroll
        for (int k = 0; k < 4; ++k) {
            float pa = a[k].x * a[k].x + a[k].y * a[k].y;
            float pb = bb[k].x * bb[k].x + bb[k].y * bb[k].y;
            sum_d[k] = pa + pb;
            dif_d[k] = pa - pb;
        }
        f2 wS[6], wD[6];
        {
            int pi = 0;
            #pragma unroll
            for (int k = 0; k < 4; ++k)
                #pragma unroll
                for (int k2 = k + 1; k2 < 4; ++k2) {
                    f2 u = cmulc(a[k], a[k2]);
                    f2 v = cmulc(bb[k], bb[k2]);
                    wS[pi] = f2{u.x + v.x, u.y + v.y};
                    wD[pi] = f2{u.x - v.x, u.y - v.y};
                    ++pi;
                }
        }

        float F[6];
        #pragma unroll
        for (int pt = 0; pt < 6; ++pt) {
            const float* Hk = sH[bsel][pt];
            float f = 0.f;
            #pragma unroll
            for (int k = 0; k < 4; ++k) f += Hk[(k * 4 + k) * 2] * sum_d[k];
            int pi = 0;
            #pragma unroll
            for (int k = 0; k < 4; ++k)
                #pragma unroll
                for (int k2 = k + 1; k2 < 4; ++k2) {
                    float hr = Hk[(k * 4 + k2) * 2], hi = Hk[(k * 4 + k2) * 2 + 1];
                    f += 2.f * (hr * wS[pi].x - hi * wS[pi].y);
                    ++pi;
                }
            F[pt] = f;
        }
        float pd_i;
        {
            const float* Dk = sD[bsel];
            const float* Ek = sE[bsel];
            float f = 0.f;
            #pragma unroll
            for (int k = 0; k < 4; ++k) f += Dk[(k * 4 + k) * 2] * dif_d[k];
            int pi = 0;
            #pragma unroll
            for (int k = 0; k < 4; ++k)
                #pragma unroll
                for (int k2 = k + 1; k2 < 4; ++k2) {
                    float dr = Dk[(k * 4 + k2) * 2], di = Dk[(k * 4 + k2) * 2 + 1];
                    f += 2.f * (dr * wD[pi].x - di * wD[pi].y);
                    ++pi;
                }
            f2 z = f2{0.f, 0.f};
            #pragma unroll
            for (int k = 0; k < 4; ++k) {
                f2 v = f2{0.f, 0.f};
                #pragma unroll
                for (int k2 = 0; k2 < 4; ++k2) {
                    float er = Ek[(k * 4 + k2) * 2], ei = Ek[(k * 4 + k2) * 2 + 1];
                    v.x += er * bb[k2].x + ei * bb[k2].y;    // E * conj(b)
                    v.y += ei * bb[k2].x - er * bb[k2].y;
                }
                z.x += a[k].x * v.x - a[k].y * v.y;
                z.y += a[k].x * v.y + a[k].y * v.x;
            }
            pd_i = f - 4.f * z.y;
        }

        Pa += F[0];
        P9 += pl ? -F[0] : F[0];          // tau bit 8 = pl
        Pd += pd_i;
        S0 += F[1]; S1 += F[2]; S2 += F[3]; S3 += F[4]; S4 += F[5];
    }

    // ---- reductions: WHT for Pa (tau bits 0-5), plain butterflies for the rest ----
    #pragma unroll
    for (int o = 1; o < 64; o <<= 1) {
        float tP = __shfl_xor(Pa, o);
        Pa = (lane & o) ? (tP - Pa) : (Pa + tP);
        Pd  += __shfl_xor(Pd, o);
        P9  += __shfl_xor(P9, o);
        S0  += __shfl_xor(S0, o);
        S1  += __shfl_xor(S1, o);
        S2  += __shfl_xor(S2, o);
        S3  += __shfl_xor(S3, o);
        S4  += __shfl_xor(S4, o);
    }
    if ((lane & (lane - 1)) == 0) {       // lanes 0,1,2,4,8,16,32
        int slot = (lane == 0) ? 0 : (31 - __clz((unsigned)lane)) + 1;  // 1..6
        redP[wv][slot] = Pa;
    }
    if (lane == 0) {
        redQ[wv][0] = Pd;  redQ[wv][1] = P9;
        redQ[wv][2] = S0;  redQ[wv][3] = S1;  redQ[wv][4] = S2;
        redQ[wv][5] = S3;  redQ[wv][6] = S4;
    }
    __syncthreads();
    if (tid < 16) {
        int q = tid;
        float v = 0.f;
        if (q == 0) {
            #pragma unroll
            for (int w = 0; w < 8; ++w) v += redQ[w][0];
        } else if (q < 7) {
            #pragma unroll
            for (int w = 0; w < 8; ++w) v += redP[w][q];
        } else if (q == 7) {        // tau b6 = wave bit 0
            #pragma unroll
            for (int w = 0; w < 8; ++w) v += (w & 1) ? -redP[w][0] : redP[w][0];
        } else if (q == 8) {        // tau b7 = wave bit 1
            #pragma unroll
            for (int w = 0; w < 8; ++w) v += (w & 2) ? -redP[w][0] : redP[w][0];
        } else if (q == 9) {        // tau b8 = pl (in-thread sign)
            #pragma unroll
            for (int w = 0; w < 8; ++w) v += redQ[w][1];
        } else if (q == 10) {       // tau b9 = wave-group
            #pragma unroll
            for (int w = 0; w < 8; ++w) v += (w & 4) ? -redP[w][0] : redP[w][0];
        } else {
            #pragma unroll
            for (int w = 0; w < 8; ++w) v += redQ[w][q - 9];
        }
        evf[q] = v;
    }
    __syncthreads();

    // ---- head: logits + log_softmax ----
    if (tid < 16) {
        int c = tid;
        float v = fcb[c];
        #pragma unroll
        for (int q = 0; q < 16; ++q) v += evf[q] * fcw[c * 16 + q];
        lgf[c] = v;
    }
    __syncthreads();
    if (tid < 16) {
        float mx = -1e30f;
        #pragma unroll
        for (int c2 = 0; c2 < 16; ++c2) mx = fmaxf(mx, lgf[c2]);
        float se = 0.f;
        #pragma unroll
        for (int c2 = 0; c2 < 16; ++c2) se += expf(lgf[c2] - mx);
        out[b * 16 + tid] = lgf[tid] - (mx + logf(se));
    }
}

// ---------------- launch ----------------
extern "C" void kernel_launch(void* const* d_in, const int* in_sizes, int n_in,
                              void* d_out, int out_size, void* d_ws, size_t ws_size,
                              hipStream_t stream) {
    const float* x    = (const float*)d_in[0];
    const float* cw   = (const float*)d_in[1];
    const float* cb   = (const float*)d_in[2];
    const float* rot1 = (const float*)d_in[3];
    const float* crx1 = (const float*)d_in[4];
    const float* rot2 = (const float*)d_in[5];
    const float* crx2 = (const float*)d_in[6];
    const float* fcw  = (const float*)d_in[7];
    const float* fcb  = (const float*)d_in[8];

    qall2<<<128, 512, 0, stream>>>(x, cw, cb, rot1, crx1, rot2, crx2,
                                   fcw, fcb, (float*)d_out);
}

// Round 18
// 26.348 us; speedup vs baseline: 4.8098x; 1.0378x over previous
//
#include <hip/hip_runtime.h>
#include <hip/hip_bf16.h>

typedef float f2 __attribute__((ext_vector_type(2)));

// ---------------- shuffle-gate: merged 2x2 gate, amp-per-lane ----------------
// u: 16 floats {U | M1}; kt = target lane-bit; kc = control lane-bit (<0: plain)
__device__ __forceinline__ f2 sgate(f2 a, int lane, int kt, int kc, const float* u) {
    f2 p;
    p.x = __shfl_xor(a.x, 1 << kt);
    p.y = __shfl_xor(a.y, 1 << kt);
    const float* uu = u + ((kc >= 0 && ((lane >> kc) & 1)) ? 8 : 0);
    int bit = (lane >> kt) & 1;
    float cAr = bit ? uu[6] : uu[0], cAi = bit ? uu[7] : uu[1];
    float cPr = bit ? uu[4] : uu[2], cPi = bit ? uu[5] : uu[3];
    f2 r;
    r.x = cAr * a.x - cAi * a.y + cPr * p.x - cPi * p.y;
    r.y = cAr * a.y + cAi * a.x + cPr * p.y + cPi * p.x;
    return r;
}

__device__ __forceinline__ f2 cmul(f2 A, f2 B) {
    return f2{A.x * B.x - A.y * B.y, A.x * B.y + A.y * B.x};
}
// x * conj(y)
__device__ __forceinline__ f2 cmulc(f2 x, f2 y) {
    return f2{x.x * y.x + x.y * y.y, x.y * y.x - x.x * y.y};
}

// ---------------- single kernel: pool + prep + quadratic forms + EV + head ----------
// grid = 128 (one block per batch), 512 threads. All tables LDS-resident.
// Phase 0: waves 0-3 pool (BW-saturating); waves 4-7 precompute weight-only trig.
__global__ __launch_bounds__(512) void qall2(const float* __restrict__ x,
                                             const float* __restrict__ cw,
                                             const float* __restrict__ cb,
                                             const float* __restrict__ rot1,
                                             const float* __restrict__ crx1,
                                             const float* __restrict__ rot2,
                                             const float* __restrict__ crx2,
                                             const float* __restrict__ fcw,
                                             const float* __restrict__ fcb,
                                             float* __restrict__ out) {
    __shared__ float pp[32];
    __shared__ float rotS[32][8];    // weight-only Rot matrix entries per (q,l)
    __shared__ float crxS[32][2];    // CRX(q-1,q) c/s per (q,l) (q>=1); q=0 unused
    __shared__ float uM[32][16];     // [l*16+q] merged {U | RX(crx[q-1])U}
    __shared__ float cs15[4];        // [l0 c,s | l1 c,s] for CRX(15,0)
    __shared__ f2 ell[64];
    __shared__ f2 Rr[2][64];
    __shared__ f2 Wl[2][32];
    __shared__ f2 Btab[4][64];       // [c*2+p][x]
    __shared__ f2 Ctab[8][32];       // [(p*2+j)*2+p2][y]
    __shared__ float Rtab[2][4][64]; // [bsel][c*2+j][2m+ri]
    __shared__ float sH[2][6][32];   // Gram mats (pt: P, m-bit0..4), f2-flattened
    __shared__ float sD[2][32];
    __shared__ float sE[2][32];
    __shared__ float redP[8][7];
    __shared__ float redQ[8][7];     // Pd, P9, S0..S4
    __shared__ float evf[16];
    __shared__ float lgf[16];
    int tid = threadIdx.x;
    int b = blockIdx.x;

    // ---- phase 0a: waves 0-3 pool this batch's x (512 KB, LLC-hot) ----
    if (tid < 256) {
        int g = tid >> 3, sub = tid & 7;
        int c = g >> 4, dd = (g >> 2) & 3, hh = g & 3;
        const float4* xb = (const float4*)(x + (size_t)b * 131072)
                         + c * 16384 + dd * 4096 + hh * 256;
        float sum = 0.f;
        #pragma unroll
        for (int d = 0; d < 4; ++d) {
            const float4* ch = xb + d * 1024;
            #pragma unroll 8
            for (int i = 0; i < 32; ++i) {
                float4 v = ch[i * 8 + sub];
                sum += v.x + v.y + v.z + v.w;
            }
        }
        sum += __shfl_xor(sum, 1);
        sum += __shfl_xor(sum, 2);
        sum += __shfl_xor(sum, 4);
        if (sub == 0) pp[g] = sum * (1.0f / 4096.0f);
    } else if (tid < 288) {
        // ---- phase 0b: waves 4-7 (first 32): weight-only trig per (q, l) ----
        int q = (tid - 256) & 15, l = (tid - 256) >> 4;
        const float* rw = (l == 0 ? rot1 : rot2) + q * 3;
        float phi = rw[0], th = rw[1], om = rw[2];
        float ct = cosf(0.5f * th), st = sinf(0.5f * th);
        float aa = 0.5f * (phi + om), dd = 0.5f * (phi - om);
        float ca = cosf(aa), sa = sinf(aa), cd = cosf(dd), sd = sinf(dd);
        float* rs = rotS[l * 16 + q];
        rs[0] =  ct * ca;  rs[1] = -ct * sa;     // R00
        rs[2] = -st * cd;  rs[3] = -st * sd;     // R01
        rs[4] =  st * cd;  rs[5] = -st * sd;     // R10
        rs[6] =  ct * ca;  rs[7] =  ct * sa;     // R11
        if (q >= 1) {
            float thc = (l == 0 ? crx1 : crx2)[q - 1];
            crxS[l * 16 + q][0] = cosf(0.5f * thc);
            crxS[l * 16 + q][1] = sinf(0.5f * thc);
        }
        if (q == 15) {
            float th2 = (l == 0 ? crx1 : crx2)[15];
            cs15[l * 2]     = cosf(0.5f * th2);
            cs15[l * 2 + 1] = sinf(0.5f * th2);
        }
    }
    __syncthreads();

    // ---- merged gate matrices: 32 threads, one per (q, l) ----
    if (tid < 32) {
        int q = tid & 15, l = tid >> 4;
        float f = cb[q];
        #pragma unroll
        for (int jj = 0; jj < 32; ++jj) f += pp[jj] * cw[q * 32 + jj];
        float cr = cosf(0.5f * f), sr = sinf(0.5f * f);
        const float* rs = rotS[l * 16 + q];
        float R00r = rs[0], R00i = rs[1];
        float R01r = rs[2], R01i = rs[3];
        float R10r = rs[4], R10i = rs[5];
        float R11r = rs[6], R11i = rs[7];
        float u0 = cr * R00r + sr * R01i;
        float u1 = cr * R00i - sr * R01r;
        float u2 = cr * R01r + sr * R00i;
        float u3 = cr * R01i - sr * R00r;
        float u4 = cr * R10r + sr * R11i;
        float u5 = cr * R10i - sr * R11r;
        float u6 = cr * R11r + sr * R10i;
        float u7 = cr * R11i - sr * R10r;
        float g[16];
        g[0] = u0; g[1] = u1; g[2] = u2; g[3] = u3;
        g[4] = u4; g[5] = u5; g[6] = u6; g[7] = u7;
        if (q >= 1) {
            float c2 = crxS[l * 16 + q][0], s2 = crxS[l * 16 + q][1];
            g[8]  = c2*u0 + s2*u5;  g[9]  = c2*u1 - s2*u4;
            g[10] = c2*u2 + s2*u7;  g[11] = c2*u3 - s2*u6;
            g[12] = c2*u4 + s2*u1;  g[13] = c2*u5 - s2*u0;
            g[14] = c2*u6 + s2*u3;  g[15] = c2*u7 - s2*u2;
        } else {
            #pragma unroll
            for (int k = 0; k < 8; ++k) g[8 + k] = g[k];
        }
        float* s = uM[l * 16 + q];
        #pragma unroll
        for (int k = 0; k < 16; ++k) s[k] = g[k];
    }
    __syncthreads();

    int wv = tid >> 6, lane = tid & 63;

    // ---- stage A (waves 0-3 only) ----
    if (wv == 0) {
        f2 a = (lane == 0) ? f2{1.f, 0.f} : f2{0.f, 0.f};
        a = sgate(a, lane, 0, -1, uM[0]);                 // L0 G0
        #pragma unroll
        for (int q = 1; q <= 5; ++q) a = sgate(a, lane, q, q - 1, uM[q]);
        ell[lane] = a;
    } else if (wv <= 2) {
        int pidx = wv - 1;
        const float* m6 = uM[6] + pidx * 8;               // M_p = L0-G6 variant
        f2 a = f2{0.f, 0.f};
        if (lane == 0) a = f2{m6[0], m6[1]};
        if (lane == 1) a = f2{m6[4], m6[5]};
        #pragma unroll
        for (int q = 7; q <= 11; ++q) a = sgate(a, lane, q - 6, q - 7, uM[q]);
        Rr[pidx][lane] = a;
    } else if (wv == 3) {
        int j = lane >> 5, lm = lane & 31;
        f2 a = (lm == j) ? f2{1.f, 0.f} : f2{0.f, 0.f};   // e_j at bit11 (m bit 0)
        #pragma unroll
        for (int q = 12; q <= 15; ++q) a = sgate(a, lane, q - 11, q - 12, uM[q]);
        Wl[j][lm] = a;
    }
    __syncthreads();

    // ---- stage B (waves 0-3 only) ----
    if (wv < 4) {
        {   // B_{c,p}: c = wv>>1, p = wv&1
            int c = wv >> 1, pb = wv & 1;
            f2 a = ell[lane];
            if (((lane >> 5) & 1) != pb) a = f2{0.f, 0.f};    // P_p on bit 5
            if (c) {                                          // RX0(L0 crx15) on bit 0
                f2 pr; pr.x = __shfl_xor(a.x, 1); pr.y = __shfl_xor(a.y, 1);
                f2 n = cs15[0] * a;
                n.x += cs15[1] * pr.y; n.y -= cs15[1] * pr.x;
                a = n;
            }
            a = sgate(a, lane, 0, -1, uM[16]);                // L1 G0
            #pragma unroll
            for (int q = 1; q <= 5; ++q) a = sgate(a, lane, q, q - 1, uM[16 + q]);
            Btab[wv][lane] = a;
        }
        {   // C_{p,j,p2}: p = wv>>1, p2 = wv&1, halves j
            int pidx = wv >> 1, p2 = wv & 1, j = lane >> 5, lm = lane & 31;
            f2 a = Rr[pidx][(j << 5) | lm];                   // restrict bit11 = j
            a = sgate(a, lane, 0, -1, uM[16 + 6] + p2 * 8);   // M_{p2} = L1-G6 variant
            #pragma unroll
            for (int q = 7; q <= 10; ++q) a = sgate(a, lane, q - 6, q - 7, uM[16 + q]);
            Ctab[(pidx * 2 + j) * 2 + p2][lm] = a;
        }
        {   // R_{c,j}^{bsel}: c = wv>>1, bsel = wv&1, halves j
            int c = wv >> 1, bsel = wv & 1, j = lane >> 5, lm = lane & 31;
            f2 a = Wl[j][lm];
            if (((lm >> 4) & 1) != c) a = f2{0.f, 0.f};       // mask bit15 = c
            a = sgate(a, lane, 0, -1, uM[16 + 11] + bsel * 8);  // L1 G11^{bsel}
            #pragma unroll
            for (int q = 12; q <= 15; ++q) a = sgate(a, lane, q - 11, q - 12, uM[16 + q]);
            Rtab[bsel][c * 2 + j][2 * lm]     = a.x;
            Rtab[bsel][c * 2 + j][2 * lm + 1] = a.y;
        }
    }
    __syncthreads();

    // ---- Gram matrices: 192 threads, one per (bsel, pattern, k, k2) -> LDS ----
    if (tid < 192) {
        int bsel = tid / 96, rem = tid % 96, pt = rem >> 4, kk = rem & 15;
        int k = kk >> 2, k2 = kk & 3;
        float c15 = cs15[2], s15 = cs15[3];
        f2 Elo = f2{0.f, 0.f}, Ehi = f2{0.f, 0.f};
        #pragma unroll
        for (int m = 0; m < 32; ++m) {
            float rk = Rtab[bsel][k][2 * m],  ik = Rtab[bsel][k][2 * m + 1];
            float rp = Rtab[bsel][k2][2 * m], ip = Rtab[bsel][k2][2 * m + 1];
            float sg = (pt == 0) ? 1.f : (((m >> (pt - 1)) & 1) ? -1.f : 1.f);
            float wr = sg * (rk * rp + ik * ip);     // R_k * conj(R_k2)
            float wi = sg * (ik * rp - rk * ip);
            if (m < 16) { Elo.x += wr; Elo.y += wi; }
            else        { Ehi.x += wr; Ehi.y += wi; }
        }
        sH[bsel][pt][2 * kk]     = Elo.x + Ehi.x;
        sH[bsel][pt][2 * kk + 1] = Elo.y + Ehi.y;
        if (pt == 0) {
            float ccss = c15 * c15 - s15 * s15;
            sD[bsel][2 * kk]     = Elo.x + ccss * Ehi.x;
            sD[bsel][2 * kk + 1] = Elo.y + ccss * Ehi.y;
            float cs = c15 * s15;
            sE[bsel][2 * kk]     = cs * Ehi.x;
            sE[bsel][2 * kk + 1] = cs * Ehi.y;
        }
    }
    __syncthreads();

    // ---- phase 2: wave-group g handles parts {2g, 2g+1}; tau = part*256 + sub ----
    int sub = tid & 255;
    int grp = tid >> 8;                 // tau bit 9 = bsel
    int x0 = 2 * (sub & 31), x1 = x0 + 1;
    int x5 = (sub >> 4) & 1;

    f2 B0[2][2], B1[2][2];
    #pragma unroll
    for (int c = 0; c < 2; ++c)
        #pragma unroll
        for (int pq = 0; pq < 2; ++pq) {
            B0[c][pq] = Btab[c * 2 + pq][x0];
            B1[c][pq] = Btab[c * 2 + pq][x1];
        }

    float Pa = 0.f, P9 = 0.f, Pd = 0.f;
    float S0 = 0.f, S1 = 0.f, S2 = 0.f, S3 = 0.f, S4 = 0.f;

    #pragma unroll
    for (int pl = 0; pl < 2; ++pl) {
        int part = grp * 2 + pl;
        int bsel = grp;
        int y = part * 8 + (sub >> 5);
        f2 Cv[2][2];
        #pragma unroll
        for (int pq = 0; pq < 2; ++pq)
            #pragma unroll
            for (int j = 0; j < 2; ++j)
                Cv[pq][j] = Ctab[(pq * 2 + j) * 2 + x5][y];

        f2 a[4], bb[4];
        #pragma unroll
        for (int c = 0; c < 2; ++c)
            #pragma unroll
            for (int j = 0; j < 2; ++j) {
                f2 s0 = cmul(B0[c][0], Cv[0][j]);
                f2 s1 = cmul(B0[c][1], Cv[1][j]);
                a[c * 2 + j] = f2{s0.x + s1.x, s0.y + s1.y};
                f2 t0 = cmul(B1[c][0], Cv[0][j]);
                f2 t1 = cmul(B1[c][1], Cv[1][j]);
                bb[c * 2 + j] = f2{t0.x + t1.x, t0.y + t1.y};
            }

        float sum_d[4], dif_d[4];
        #pragma unroll
        for (int k = 0; k < 4; ++k) {
            float pa = a[k].x * a[k].x + a[k].y * a[k].y;
            float pb = bb[k].x * bb[k].x + bb[k].y * bb[k].y;
            sum_d[k] = pa + pb;
            dif_d[k] = pa - pb;
        }
        f2 wS[6], wD[6];
        {
            int pi = 0;
            #pragma unroll
            for (int k = 0; k < 4; ++k)
                #pragma unroll
                for (int k2 = k + 1; k2 < 4; ++k2) {
                    f2 u = cmulc(a[k], a[k2]);
                    f2 v = cmulc(bb[k], bb[k2]);
                    wS[pi] = f2{u.x + v.x, u.y + v.y};
                    wD[pi] = f2{u.x - v.x, u.y - v.y};
                    ++pi;
                }
        }

        float F[6];
        #pragma unroll
        for (int pt = 0; pt < 6; ++pt) {
            const float* Hk = sH[bsel][pt];
            float f = 0.f;
            #pragma unroll
            for (int k = 0; k < 4; ++k) f += Hk[(k * 4 + k) * 2] * sum_d[k];
            int pi = 0;
            #pragma unroll
            for (int k = 0; k < 4; ++k)
                #pragma unroll
                for (int k2 = k + 1; k2 < 4; ++k2) {
                    float hr = Hk[(k * 4 + k2) * 2], hi = Hk[(k * 4 + k2) * 2 + 1];
                    f += 2.f * (hr * wS[pi].x - hi * wS[pi].y);
                    ++pi;
                }
            F[pt] = f;
        }
        float pd_i;
        {
            const float* Dk = sD[bsel];
            const float* Ek = sE[bsel];
            float f = 0.f;
            #pragma unroll
            for (int k = 0; k < 4; ++k) f += Dk[(k * 4 + k) * 2] * dif_d[k];
            int pi = 0;
            #pragma unroll
            for (int k = 0; k < 4; ++k)
                #pragma unroll
                for (int k2 = k + 1; k2 < 4; ++k2) {
                    float dr = Dk[(k * 4 + k2) * 2], di = Dk[(k * 4 + k2) * 2 + 1];
                    f += 2.f * (dr * wD[pi].x - di * wD[pi].y);
                    ++pi;
                }
            f2 z = f2{0.f, 0.f};
            #pragma unroll
            for (int k = 0; k < 4; ++k) {
                f2 v = f2{0.f, 0.f};
                #pragma unroll
                for (int k2 = 0; k2 < 4; ++k2) {
                    float er = Ek[(k * 4 + k2) * 2], ei = Ek[(k * 4 + k2) * 2 + 1];
                    v.x += er * bb[k2].x + ei * bb[k2].y;    // E * conj(b)
                    v.y += ei * bb[k2].x - er * bb[k2].y;
                }
                z.x += a[k].x * v.x - a[k].y * v.y;
                z.y += a[k].x * v.y + a[k].y * v.x;
            }
            pd_i = f - 4.f * z.y;
        }

        Pa += F[0];
        P9 += pl ? -F[0] : F[0];          // tau bit 8 = pl
        Pd += pd_i;
        S0 += F[1]; S1 += F[2]; S2 += F[3]; S3 += F[4]; S4 += F[5];
    }

    // ---- reductions: WHT for Pa (tau bits 0-5), plain butterflies for the rest ----
    #pragma unroll
    for (int o = 1; o < 64; o <<= 1) {
        float tP = __shfl_xor(Pa, o);
        Pa = (lane & o) ? (tP - Pa) : (Pa + tP);
        Pd  += __shfl_xor(Pd, o);
        P9  += __shfl_xor(P9, o);
        S0  += __shfl_xor(S0, o);
        S1  += __shfl_xor(S1, o);
        S2  += __shfl_xor(S2, o);
        S3  += __shfl_xor(S3, o);
        S4  += __shfl_xor(S4, o);
    }
    if ((lane & (lane - 1)) == 0) {       // lanes 0,1,2,4,8,16,32
        int slot = (lane == 0) ? 0 : (31 - __clz((unsigned)lane)) + 1;  // 1..6
        redP[wv][slot] = Pa;
    }
    if (lane == 0) {
        redQ[wv][0] = Pd;  redQ[wv][1] = P9;
        redQ[wv][2] = S0;  redQ[wv][3] = S1;  redQ[wv][4] = S2;
        redQ[wv][5] = S3;  redQ[wv][6] = S4;
    }
    __syncthreads();
    if (tid < 16) {
        int q = tid;
        float v = 0.f;
        if (q == 0) {
            #pragma unroll
            for (int w = 0; w < 8; ++w) v += redQ[w][0];
        } else if (q < 7) {
            #pragma unroll
            for (int w = 0; w < 8; ++w) v += redP[w][q];
        } else if (q == 7) {        // tau b6 = wave bit 0
            #pragma unroll
            for (int w = 0; w < 8; ++w) v += (w & 1) ? -redP[w][0] : redP[w][0];
        } else if (q == 8) {        // tau b7 = wave bit 1
            #pragma unroll
            for (int w = 0; w < 8; ++w) v += (w & 2) ? -redP[w][0] : redP[w][0];
        } else if (q == 9) {        // tau b8 = pl (in-thread sign)
            #pragma unroll
            for (int w = 0; w < 8; ++w) v += redQ[w][1];
        } else if (q == 10) {       // tau b9 = wave-group
            #pragma unroll
            for (int w = 0; w < 8; ++w) v += (w & 4) ? -redP[w][0] : redP[w][0];
        } else {
            #pragma unroll
            for (int w = 0; w < 8; ++w) v += redQ[w][q - 9];
        }
        evf[q] = v;
    }
    __syncthreads();

    // ---- head: logits + log_softmax ----
    if (tid < 16) {
        int c = tid;
        float v = fcb[c];
        #pragma unroll
        for (int q = 0; q < 16; ++q) v += evf[q] * fcw[c * 16 + q];
        lgf[c] = v;
    }
    __syncthreads();
    if (tid < 16) {
        float mx = -1e30f;
        #pragma unroll
        for (int c2 = 0; c2 < 16; ++c2) mx = fmaxf(mx, lgf[c2]);
        float se = 0.f;
        #pragma unroll
        for (int c2 = 0; c2 < 16; ++c2) se += expf(lgf[c2] - mx);
        out[b * 16 + tid] = lgf[tid] - (mx + logf(se));
    }
}

// ---------------- launch ----------------
extern "C" void kernel_launch(void* const* d_in, const int* in_sizes, int n_in,
                              void* d_out, int out_size, void* d_ws, size_t ws_size,
                              hipStream_t stream) {
    const float* x    = (const float*)d_in[0];
    const float* cw   = (const float*)d_in[1];
    const float* cb   = (const float*)d_in[2];
    const float* rot1 = (const float*)d_in[3];
    const float* crx1 = (const float*)d_in[4];
    const float* rot2 = (const float*)d_in[5];
    const float* crx2 = (const float*)d_in[6];
    const float* fcw  = (const float*)d_in[7];
    const float* fcb  = (const float*)d_in[8];

    qall2<<<128, 512, 0, stream>>>(x, cw, cb, rot1, crx1, rot2, crx2,
                                   fcw, fcb, (float*)d_out);
}